// Round 13
// baseline (650.394 us; speedup 1.0000x reference)
//
#include <hip/hip_runtime.h>

#define B_   16
#define TXT  32
#define VID  2048
#define D_   256
#define S_   2080
#define SP   2176   // padded sequence rows (34 tiles of 64)
#define NKT  34     // tiles (64 rows each) in Q/K/V subtiled layouts
#define GTOT 17424  // 16 b * 33 qt * 33 kv global iterations

typedef unsigned short ushort_t;
typedef __attribute__((ext_vector_type(8))) short short8;
typedef __attribute__((ext_vector_type(4))) short short4v;
typedef __attribute__((ext_vector_type(4))) float f32x4;
typedef __attribute__((ext_vector_type(16))) float f32x16;

__device__ __forceinline__ ushort_t f2bf(float f) {
  unsigned u = __builtin_bit_cast(unsigned, f);
  unsigned r = (u + 0x7FFFu + ((u >> 16) & 1u)) >> 16;   // RNE (finite values)
  return (ushort_t)r;
}
__device__ __forceinline__ float bf2f(ushort_t h) {
  unsigned u = ((unsigned)h) << 16;
  return __builtin_bit_cast(float, u);
}

__device__ __forceinline__ void g2l16(void* lds, const void* g) {
  __builtin_amdgcn_global_load_lds(
      (const __attribute__((address_space(1))) char*)g,
      (__attribute__((address_space(3))) char*)lds, 16, 0, 0);
}

__device__ __forceinline__ f32x4 mfma16(short8 a, short8 b, f32x4 c) {
  return __builtin_amdgcn_mfma_f32_16x16x32_bf16(a, b, c, 0, 0, 0);
}
__device__ __forceinline__ f32x16 mfma32(short8 a, short8 b, f32x16 c) {
  return __builtin_amdgcn_mfma_f32_32x32x16_bf16(a, b, c, 0, 0, 0);
}

// Subtiled layouts (per batch, per 64-row tile, 32KB = 16384 ushorts), all PLAIN:
//   Q/K: [kstep16][64 row][16 us]   (wave fragment reads are contiguous 1KB)
//   V:   [kvstep4][256 d][16 us]
// tile base (ushorts): (b*NKT + tile) << 14

// ---------------- merged producer kernel ----------------
// blocks: [0,64) txt | [64,112) wt | [112,1136) tbl | [1136,1328) pad0 | [1328,3376) sig
__global__ void prep_kernel(const float* __restrict__ src, const float* __restrict__ learn,
                            const float* __restrict__ Wtq, const float* __restrict__ Wtk,
                            const float* __restrict__ Wtv,
                            const float* __restrict__ Wvq, const float* __restrict__ Wvk,
                            const float* __restrict__ Wvv,
                            ushort_t* __restrict__ Qs, ushort_t* __restrict__ Ks,
                            ushort_t* __restrict__ VTs, ushort_t* __restrict__ sigp,
                            float* __restrict__ tbl, ushort_t* __restrict__ WT,
                            float* __restrict__ loss) {
  __shared__ float shf[64 * 68];          // aliased per branch
  const int blk = blockIdx.x;
  const int tid = threadIdx.x;

  if (blk < 64) {
    // ---- txt rows: Q/K = (pos+x)W, V = xW ----
    float (*a_s)[256] = (float(*)[256])shf;
    float (*x_s)[256] = (float(*)[256])(shf + 2048);
    const int tg = blk & 3;
    const int b  = blk >> 2;
    const int c  = tid;
    #pragma unroll
    for (int t = 0; t < 8; ++t) {
      int row = tg * 8 + t;
      float x = src[((size_t)b * S_ + row) * D_ + c];
      float xe = (float)(row + 1) * (6.283185307179586f / (32.0f + 1e-6f));
      int i = c >> 1;
      float dimt = powf(10000.0f, (2.0f * (float)i) / 256.0f);
      float ang = xe / dimt;
      float pv = (c & 1) ? cosf(ang) : sinf(ang);
      x_s[t][c] = x;
      a_s[t][c] = x + pv;
    }
    __syncthreads();
    float q[8] = {0,0,0,0,0,0,0,0}, k[8] = {0,0,0,0,0,0,0,0}, v[8] = {0,0,0,0,0,0,0,0};
    for (int kk = 0; kk < 256; ++kk) {
      float wq = Wtq[(size_t)kk * 256 + c];
      float wk = Wtk[(size_t)kk * 256 + c];
      float wv = Wtv[(size_t)kk * 256 + c];
      #pragma unroll
      for (int t = 0; t < 8; ++t) {
        q[t] = fmaf(a_s[t][kk], wq, q[t]);
        k[t] = fmaf(a_s[t][kk], wk, k[t]);
        v[t] = fmaf(x_s[t][kk], wv, v[t]);
      }
    }
    #pragma unroll
    for (int t = 0; t < 8; ++t) {
      int row = tg * 8 + t;          // rows 0..31 => tile 0
      size_t base = ((size_t)(b * NKT)) << 14;
      size_t sub = (size_t)(c >> 4) * 1024 + row * 16 + (c & 15);
      Qs[base + sub] = f2bf(q[t]);
      Ks[base + sub] = f2bf(k[t]);
      VTs[base + (size_t)(row >> 4) * 4096 + c * 16 + (row & 15)] = f2bf(v[t]);
    }
  } else if (blk < 112) {
    // ---- weight transpose: WT[mat][n][k] = W[k][n] ----
    float (*t)[68] = (float(*)[68])shf;
    const int m = blk - 64;
    const int k0 = (m & 3) * 64, n0 = ((m >> 2) & 3) * 64, mt = m >> 4;
    const float* W = (mt == 0) ? Wvq : (mt == 1) ? Wvk : Wvv;
    int r = tid >> 4, cq = (tid & 15) * 4;
    #pragma unroll
    for (int mm = 0; mm < 4; ++mm) {
      int k = mm * 16 + r;
      float4 v = *(const float4*)(W + (size_t)(k0 + k) * 256 + n0 + cq);
      t[k][cq] = v.x; t[k][cq + 1] = v.y; t[k][cq + 2] = v.z; t[k][cq + 3] = v.w;
    }
    __syncthreads();
    #pragma unroll
    for (int mm = 0; mm < 4; ++mm) {
      int n = mm * 16 + r;
      short4v h;
      h[0] = (short)f2bf(t[cq + 0][n]);
      h[1] = (short)f2bf(t[cq + 1][n]);
      h[2] = (short)f2bf(t[cq + 2][n]);
      h[3] = (short)f2bf(t[cq + 3][n]);
      *(short4v*)(WT + ((size_t)mt * D_ + n0 + n) * D_ + k0 + cq) = h;
    }
  } else if (blk < 1136) {
    // ---- xpos table ----
    int idx = (blk - 112) * 256 + tid;
    int n = idx >> 7, i = idx & 127;
    float invf = powf(10000.0f, -(float)i / 128.0f);
    float ang = (float)n * invf;
    float s, co;
    sincosf(ang, &s, &co);
    float sv = ((float)(2 * i) + 102.4f) / 358.4f;
    float sc = powf(sv, (float)n / 512.0f);
    float4 r;
    r.x = co * sc; r.y = s * sc; r.z = co / sc; r.w = s / sc;
    *(float4*)(tbl + (size_t)idx * 4) = r;
  } else if (blk < 1328) {
    // ---- zero-fill padding (tile 32: Q/K rows 32..63, V kvsteps 2..3) ----
    int i = (blk - 1136) * 256 + tid;           // 49152 total
    short8 z = {0, 0, 0, 0, 0, 0, 0, 0};
    int sec = i >> 14;
    int j = i & 16383;
    int bb = j >> 10;
    int rem = j & 1023;
    size_t base = ((size_t)(bb * NKT + 32)) << 14;
    if (sec == 0) {
      int kstep = rem >> 6, ch = rem & 63;
      *(short8*)(Qs + base + kstep * 1024 + 512 + ch * 8) = z;
    } else if (sec == 1) {
      int kstep = rem >> 6, ch = rem & 63;
      *(short8*)(Ks + base + kstep * 1024 + 512 + ch * 8) = z;
    } else {
      *(short8*)(VTs + base + 8192 + rem * 8) = z;
    }
  } else {
    // ---- sigmoid mask (row-major bf16) + sparsity loss ----
    float* red = shf;
    const int base = ((blk - 1328) * 256 + tid) * 8;
    float4 v0 = *(const float4*)(learn + base);
    float4 v1 = *(const float4*)(learn + base + 4);
    float vals[8] = {v0.x, v0.y, v0.z, v0.w, v1.x, v1.y, v1.z, v1.w};
    float acc = 0.f;
    short8 sh;
    #pragma unroll
    for (int j = 0; j < 8; ++j) {
      int idx = base + j;
      float s = 1.0f / (1.0f + expf(-vals[j]));
      sh[j] = (short)f2bf(s);
      int rr = idx >> 11, cc = idx & 2047;
      if (rr != cc) acc += s;
    }
    *(short8*)(sigp + base) = sh;
    red[tid] = acc;
    __syncthreads();
    #pragma unroll
    for (int st = 128; st > 0; st >>= 1) {
      if (tid < st) red[tid] += red[tid + st];
      __syncthreads();
    }
    if (tid == 0) atomicAdd(loss, red[0] * (1.0f / 4194304.0f));
  }
}

// ---------------- src vid rows -> bf16 ----------------
__global__ void cvt_kernel(const float* __restrict__ src, ushort_t* __restrict__ srcb) {
  int i = blockIdx.x * 256 + threadIdx.x;
  int b = i >> 16;
  int rem = i & 65535;
  int row = rem >> 5, c8 = (rem & 31) * 8;
  const float* p = src + ((size_t)b * S_ + TXT + row) * D_ + c8;
  float4 v0 = *(const float4*)p;
  float4 v1 = *(const float4*)(p + 4);
  short8 h;
  h[0] = (short)f2bf(v0.x); h[1] = (short)f2bf(v0.y); h[2] = (short)f2bf(v0.z); h[3] = (short)f2bf(v0.w);
  h[4] = (short)f2bf(v1.x); h[5] = (short)f2bf(v1.y); h[6] = (short)f2bf(v1.z); h[7] = (short)f2bf(v1.w);
  *(short8*)(srcb + ((size_t)b * VID + row) * D_ + c8) = h;
}

// ---------------- vid projection GEMM (per-tile grid, +xpos epilogue) ----------------
// MODE 0: A from f32 src (cvt in-kernel).  MODE 1: A via g2l16 from bf16 srcb (pre-XOR'd source).
template <int MODE>
__global__ __launch_bounds__(256, 2) void vid_gemm(
    const float* __restrict__ src, const ushort_t* __restrict__ srcb,
    const ushort_t* __restrict__ WT, const float* __restrict__ tbl,
    ushort_t* __restrict__ Qs, ushort_t* __restrict__ Ks, ushort_t* __restrict__ VTs) {
  __shared__ __align__(16) ushort_t ldsA[64 * 64];
  __shared__ __align__(16) ushort_t ldsB[64 * 64];

  const int rt = blockIdx.x;
  const int b  = blockIdx.y;
  const int ct = blockIdx.z;
  const int nt = ct >> 2;
  const int n0 = (ct & 3) * 64;
  const int tid = threadIdx.x;
  const int wv = tid >> 6, lane = tid & 63, l15 = lane & 15, l4 = lane >> 4;

  f32x4 acc[4];
  #pragma unroll
  for (int t2 = 0; t2 < 4; ++t2) { acc[t2][0] = 0.f; acc[t2][1] = 0.f; acc[t2][2] = 0.f; acc[t2][3] = 0.f; }

  for (int kk = 0; kk < 256; kk += 64) {
    if (MODE == 1) {
      #pragma unroll
      for (int m = 0; m < 2; ++m) {
        int p = (m * 256 + tid) * 16;
        int r = p >> 7;
        int cb = (p & 127) ^ ((r & 7) << 4);
        g2l16((char*)ldsA + p,
              (const char*)(srcb + ((size_t)b * VID + rt * 64 + r) * D_ + kk) + cb);
      }
    } else {
      #pragma unroll
      for (int m = 0; m < 4; ++m) {
        int q = m * 256 + tid;
        int r = q >> 4;
        int kc = (q & 15) * 4;
        const float4 v = *(const float4*)(src + ((size_t)b * S_ + TXT + rt * 64 + r) * D_ + kk + kc);
        short4v h;
        h[0] = (short)f2bf(v.x); h[1] = (short)f2bf(v.y);
        h[2] = (short)f2bf(v.z); h[3] = (short)f2bf(v.w);
        int off = ((r << 7) + (kc << 1)) ^ ((r & 7) << 4);
        *(short4v*)((char*)ldsA + off) = h;
      }
    }
    #pragma unroll
    for (int m = 0; m < 2; ++m) {
      int p = (m * 256 + tid) * 16;
      int nl = p >> 7;
      int c = (p & 127) ^ ((nl & 7) << 4);
      g2l16((char*)ldsB + p, (const char*)(WT + ((size_t)nt * D_ + n0 + nl) * D_ + kk) + c);
    }
    __syncthreads();
    #pragma unroll
    for (int ks = 0; ks < 2; ++ks) {
      int ar = wv * 16 + l15;
      int aoff = ((ar << 7) + ((ks * 32 + l4 * 8) << 1)) ^ ((ar & 7) << 4);
      short8 av = *(const short8*)((const char*)ldsA + aoff);
      #pragma unroll
      for (int t2 = 0; t2 < 4; ++t2) {
        int nl = t2 * 16 + l15;
        int boff = ((nl << 7) + ((ks * 32 + l4 * 8) << 1)) ^ ((nl & 7) << 4);
        short8 bv = *(const short8*)((const char*)ldsB + boff);
        acc[t2] = mfma16(av, bv, acc[t2]);
      }
    }
    __syncthreads();
  }

  const int rowl = wv * 16 + l4 * 4;
  if (nt < 2) {
    #pragma unroll
    for (int t2 = 0; t2 < 4; ++t2) {
      int c = n0 + t2 * 16 + l15;
      #pragma unroll
      for (int r = 0; r < 4; ++r) {
        int n = rt * 64 + rowl + r;
        float x = acc[t2][r];
        float xp = __shfl_xor(x, 1);
        const float4 tb = *(const float4*)(tbl + ((size_t)n * 128 + (c >> 1)) * 4);
        float cs = (nt == 0) ? tb.x : tb.z;
        float ss = (nt == 0) ? tb.y : tb.w;
        float val = (c & 1) ? fmaf(x, cs, xp * ss) : fmaf(x, cs, -xp * ss);
        int rowg = TXT + n;
        size_t idx = (((size_t)(b * NKT + (rowg >> 6))) << 14)
                   + (size_t)(c >> 4) * 1024 + (rowg & 63) * 16 + (c & 15);
        if (nt == 0) Qs[idx] = f2bf(val);
        else         Ks[idx] = f2bf(val);
      }
    }
  } else {
    #pragma unroll
    for (int t2 = 0; t2 < 4; ++t2)
      #pragma unroll
      for (int r = 0; r < 4; ++r) {
        int rr = rowl + r;
        int cc = t2 * 16 + l15;
        int off = ((rr << 7) + (cc << 1)) ^ ((rr & 7) << 4);
        *(ushort_t*)((char*)ldsA + off) = f2bf(acc[t2][r]);
      }
    __syncthreads();
    int n = tid >> 2;
    int rc = (tid & 3) * 16;
    short8 o0, o1;
    #pragma unroll
    for (int j = 0; j < 8; ++j) {
      int rr = rc + j;
      int off = ((rr << 7) + (n << 1)) ^ ((rr & 7) << 4);
      o0[j] = *(const short*)((const char*)ldsA + off);
    }
    #pragma unroll
    for (int j = 0; j < 8; ++j) {
      int rr = rc + 8 + j;
      int off = ((rr << 7) + (n << 1)) ^ ((rr & 7) << 4);
      o1[j] = *(const short*)((const char*)ldsA + off);
    }
    int d = n0 + n;
    int kvg0 = TXT + rt * 64 + rc;
    size_t base = (((size_t)(b * NKT + (kvg0 >> 6))) << 14) + ((kvg0 >> 4) & 3) * 4096 + d * 16;
    *(short8*)(VTs + base) = o0;
    *(short8*)(VTs + base + 8) = o1;
  }
}

// ---------------- fused masked attention v13: 40KB LDS, 4 blocks/CU ----------------
// r12 structure minus V staging: V read DIRECT from global (zero intra-block reuse;
// contiguous 1KB coalesced wave-reads, L2-resident). K stays LDS-staged (4-wave reuse).
// 2 barriers/iter. Masks as 4x int2 (exact bytes). launch_bounds(256,4): 4 blocks/CU
// (VGPR cap 128; r12 needed 120).
__global__ __launch_bounds__(256, 4) void attn_kernel(
    const ushort_t* __restrict__ Qs, const ushort_t* __restrict__ Ks,
    const ushort_t* __restrict__ VTs, const ushort_t* __restrict__ sigp,
    float* __restrict__ out) {
  __shared__ __align__(16) ushort_t Kb[16384];      // 32KB  K(t)
  __shared__ __align__(16) ushort_t Pb[4096];       // 8KB   [32 rows][256B], XOR swz

  const int kblk = blockIdx.x;                      // 0..511
  const int bs = (kblk & 7) * 64 + (kblk >> 3);     // XCD-chunked bijective swizzle
  int g = bs * 34 + (bs >> 5);
  const int gend = (bs + 1) * 34 + ((bs + 1) >> 5);

  const int tid = threadIdx.x;
  const int wid = tid >> 6, lane = tid & 63;
  const int l31 = lane & 31, l5 = lane >> 5;
  const int qh = wid >> 1, kh = wid & 1;            // QK quarter
  const int d0 = wid * 64;                          // PV d-slice
  const int qloc = qh * 32 + l31;
  const int pkey = (l31 & 15) << 4;                 // 4-bit involutive XOR key

  int b = g / 1089, rem = g - b * 1089, qt = rem / 33, kvt = rem - qt * 33;

  short8 qf[16];
  int2 mq[4];

  auto ldq = [&](int bb, int qq) {
    const ushort_t* qb = Qs + (((size_t)(bb * NKT + qq)) << 14) + qloc * 16 + l5 * 8;
    #pragma unroll
    for (int ks = 0; ks < 16; ++ks) qf[ks] = *(const short8*)(qb + ks * 1024);
  };
  auto ldmask = [&](int qq, int tt) {
    int q = qq * 64 + qloc;
    int qc = q - TXT; qc = qc < 0 ? 0 : (qc > 2047 ? 2047 : qc);
    int kvp = tt * 64 + kh * 32 - TXT;
    int kvc = (kvp >= 0 && kvp <= 2016) ? kvp : 0;
    const char* mrow = (const char*)(sigp + (size_t)qc * 2048 + kvc) + l5 * 8;
    #pragma unroll
    for (int t = 0; t < 4; ++t) mq[t] = *(const int2*)(mrow + 16 * t);
  };
  auto stageK = [&](int bb, int tt) {
    const char* src = (const char*)Ks + (((size_t)(bb * NKT + tt)) << 15);
    #pragma unroll
    for (int m = 0; m < 8; ++m) { int s2 = m * 256 + tid; g2l16((char*)Kb + s2 * 16, src + s2 * 16); }
  };

  f32x16 oacc[2][2];
  #pragma unroll
  for (int i2 = 0; i2 < 2; ++i2)
    #pragma unroll
    for (int j2 = 0; j2 < 2; ++j2)
      #pragma unroll
      for (int r = 0; r < 16; ++r) oacc[i2][j2][r] = 0.f;

  auto flushO = [&](int bb, int qq) {
    #pragma unroll
    for (int qg2 = 0; qg2 < 2; ++qg2)
      #pragma unroll
      for (int dg = 0; dg < 2; ++dg)
        #pragma unroll
        for (int r = 0; r < 16; ++r) {
          int qg = qq * 64 + qg2 * 32 + (r & 3) + 8 * (r >> 2) + 4 * l5;
          int dd = d0 + dg * 32 + l31;
          if (qg < S_)
            unsafeAtomicAdd(&out[((size_t)bb * S_ + qg) * D_ + dd], oacc[qg2][dg][r]);
          oacc[qg2][dg][r] = 0.f;
        }
  };

  // ---- prologue ----
  stageK(b, kvt);
  ldmask(qt, kvt);
  ldq(b, qt);
  asm volatile("s_waitcnt vmcnt(0)" ::: "memory");
  __builtin_amdgcn_sched_barrier(0);
  __builtin_amdgcn_s_barrier();
  __builtin_amdgcn_sched_barrier(0);

  while (g < gend) {
    int gn = (g + 1 < GTOT) ? g + 1 : GTOT - 1;
    int nb = gn / 1089, nrem = gn - nb * 1089, nqt = nrem / 33, nkvt = nrem - nqt * 33;

    // ---- QK (S^T = K . Q^T): 2 independent chains from LDS ----
    f32x16 s0, s1;
    #pragma unroll
    for (int r = 0; r < 16; ++r) { s0[r] = 0.f; s1[r] = 0.f; }
    const int arow = (kh * 32 + l31) * 32 + l5 * 16;
    __builtin_amdgcn_s_setprio(1);
    #pragma unroll
    for (int ks = 0; ks < 8; ++ks) {
      short8 ka = *(const short8*)((const char*)Kb + ks * 2048 + arow);
      short8 kc = *(const short8*)((const char*)Kb + (ks + 8) * 2048 + arow);
      s0 = mfma32(ka, qf[ks], s0);
      s1 = mfma32(kc, qf[ks + 8], s1);
    }
    __builtin_amdgcn_s_setprio(0);

    // ---- mask + pack P (bf16) -> Pb (row = q&31, 256B rows, 4-bit XOR) ----
    {
      int q = qt * 64 + qloc;
      bool qv = (q >= TXT) && (q < S_);
      int kvp = kvt * 64 + kh * 32 - TXT;
      bool kvv = (kvp >= 0 && kvp <= 2016);
      bool ok = qv && kvv;
      #pragma unroll
      for (int t = 0; t < 4; ++t) {
        unsigned w0p, w1p;
        {
          unsigned w = (unsigned)mq[t].x;
          float m0 = ok ? bf2f((ushort_t)(w & 0xFFFFu)) : 1.0f;
          float m1 = ok ? bf2f((ushort_t)(w >> 16)) : 1.0f;
          int r = 4 * t;
          float p0 = (s0[r] + s1[r]) * m0;
          float p1 = (s0[r + 1] + s1[r + 1]) * m1;
          asm("v_cvt_pk_bf16_f32 %0, %1, %2" : "=v"(w0p) : "v"(p0), "v"(p1));
        }
        {
          unsigned w = (unsigned)mq[t].y;
          float m0 = ok ? bf2f((ushort_t)(w & 0xFFFFu)) : 1.0f;
          float m1 = ok ? bf2f((ushort_t)(w >> 16)) : 1.0f;
          int r = 4 * t + 2;
          float p0 = (s0[r] + s1[r]) * m0;
          float p1 = (s0[r + 1] + s1[r + 1]) * m1;
          asm("v_cvt_pk_bf16_f32 %0, %1, %2" : "=v"(w1p) : "v"(p0), "v"(p1));
        }
        int off = (l31 << 8) + (((qh << 7) + (kh << 6) + (t << 4) + (l5 << 3)) ^ pkey);
        *(uint2*)((char*)Pb + off) = make_uint2(w0p, w1p);
      }
    }

    asm volatile("s_waitcnt lgkmcnt(0)" ::: "memory");   // Kb reads + Pb writes done
    __builtin_amdgcn_sched_barrier(0);
    __builtin_amdgcn_s_barrier();          // barrier 1
    __builtin_amdgcn_sched_barrier(0);

    stageK(nb, nkvt);                      // K(t+1) into freed Kb
    __builtin_amdgcn_sched_barrier(0);

    // ---- PV: O[64q x 64d-slice] += P * V, V DIRECT from global ----
    const ushort_t* vb = VTs + (((size_t)(b * NKT + kvt)) << 14) + (size_t)d0 * 16 + l5 * 8;
    __builtin_amdgcn_s_setprio(1);
    #pragma unroll
    for (int ks = 0; ks < 4; ++ks) {
      short8 vf0 = *(const short8*)(vb + ks * 4096 + l31 * 16);
      short8 vf1 = *(const short8*)(vb + ks * 4096 + (l31 + 32) * 16);
      int p0 = (l31 << 8) + ((ks * 32 + l5 * 16) ^ pkey);
      int p1 = (l31 << 8) + ((128 + ks * 32 + l5 * 16) ^ pkey);
      short8 pf0 = *(const short8*)((const char*)Pb + p0);
      short8 pf1 = *(const short8*)((const char*)Pb + p1);
      oacc[0][0] = mfma32(pf0, vf0, oacc[0][0]);
      oacc[0][1] = mfma32(pf0, vf1, oacc[0][1]);
      oacc[1][0] = mfma32(pf1, vf0, oacc[1][0]);
      oacc[1][1] = mfma32(pf1, vf1, oacc[1][1]);
    }
    __builtin_amdgcn_s_setprio(0);
    asm volatile("s_waitcnt lgkmcnt(0)" ::: "memory");   // Pb reads retired
    __builtin_amdgcn_sched_barrier(0);

    // ---- tail: masks(t+1); ensure K(t+1) landed; flush at q boundaries ----
    ldmask(nqt, nkvt);                                   // 4 loads (newest)
    __builtin_amdgcn_sched_barrier(0);
    asm volatile("s_waitcnt vmcnt(4)" ::: "memory");     // K8 done; masks flying
    __builtin_amdgcn_sched_barrier(0);
    const bool qchange = (nqt != qt || nb != b);
    if (qchange) {                          // q-tile boundary (block-uniform)
      flushO(b, qt);
      ldq(nb, nqt);
    }
    __builtin_amdgcn_sched_barrier(0);
    __builtin_amdgcn_s_barrier();          // barrier 2: K(t+1)/P ready block-wide
    __builtin_amdgcn_sched_barrier(0);

    b = nb; qt = nqt; kvt = nkvt; ++g;
  }

  flushO(b, qt);
}

extern "C" void kernel_launch(void* const* d_in, const int* in_sizes, int n_in,
                              void* d_out, int out_size, void* d_ws, size_t ws_size,
                              hipStream_t stream) {
  (void)in_sizes; (void)n_in;
  const float* src   = (const float*)d_in[0];
  const float* learn = (const float*)d_in[1];
  const float* Wtq = (const float*)d_in[2];
  const float* Wtk = (const float*)d_in[3];
  const float* Wtv = (const float*)d_in[4];
  const float* Wvq = (const float*)d_in[5];
  const float* Wvk = (const float*)d_in[6];
  const float* Wvv = (const float*)d_in[7];
  float* out = (float*)d_out;

  char* ws = (char*)d_ws;
  const size_t QKV_ONE  = (size_t)B_ * SP * D_ * 2;
  const size_t QP_OFF   = 0;
  const size_t KS_OFF   = QP_OFF + QKV_ONE;
  const size_t VT_OFF   = KS_OFF + QKV_ONE;
  const size_t SIG_OFF  = VT_OFF + QKV_ONE;
  const size_t TBL_OFF  = SIG_OFF + (size_t)VID * VID * 2;
  const size_t WT_OFF   = TBL_OFF + (size_t)VID * 128 * 4 * sizeof(float);
  const size_t SRCB_OFF = WT_OFF + (size_t)3 * D_ * D_ * 2;
  const size_t NEED_SRCB = SRCB_OFF + (size_t)B_ * VID * D_ * 2;

  ushort_t* Qs   = (ushort_t*)(ws + QP_OFF);
  ushort_t* Ks   = (ushort_t*)(ws + KS_OFF);
  ushort_t* VTs  = (ushort_t*)(ws + VT_OFF);
  ushort_t* sigp = (ushort_t*)(ws + SIG_OFF);
  float*    tbl  = (float*)(ws + TBL_OFF);
  ushort_t* WT   = (ushort_t*)(ws + WT_OFF);
  ushort_t* srcb = (ushort_t*)(ws + SRCB_OFF);
  float*    loss = out + (size_t)B_ * S_ * D_;

  hipMemsetAsync(d_out, 0, (size_t)out_size * sizeof(float), stream);  // atomics + loss
  prep_kernel<<<3376, 256, 0, stream>>>(src, learn, Wtq, Wtk, Wtv, Wvq, Wvk, Wvv,
                                        Qs, Ks, VTs, sigp, tbl, WT, loss);
  if (ws_size >= NEED_SRCB) {
    cvt_kernel<<<4096, 256, 0, stream>>>(src, srcb);
    vid_gemm<1><<<dim3(32, B_, 12), 256, 0, stream>>>(src, srcb, WT, tbl, Qs, Ks, VTs);
  } else {
    vid_gemm<0><<<dim3(32, B_, 12), 256, 0, stream>>>(src, srcb, WT, tbl, Qs, Ks, VTs);
  }
  attn_kernel<<<dim3(512), 256, 0, stream>>>(Qs, Ks, VTs, sigp, out);
}

// Round 14
// 290.729 us; speedup vs baseline: 2.2371x; 2.2371x over previous
//
#include <hip/hip_runtime.h>

#define B_   16
#define TXT  32
#define VID  2048
#define D_   256
#define S_   2080
#define SP   2176   // padded sequence rows (34 tiles of 64)
#define NKT  34     // tiles (64 rows each) in Q/K/V subtiled layouts
#define GTOT 17424  // 16 b * 33 qt * 33 kv global iterations

typedef unsigned short ushort_t;
typedef __attribute__((ext_vector_type(8))) short short8;
typedef __attribute__((ext_vector_type(4))) short short4v;
typedef __attribute__((ext_vector_type(4))) float f32x4;
typedef __attribute__((ext_vector_type(16))) float f32x16;

__device__ __forceinline__ ushort_t f2bf(float f) {
  unsigned u = __builtin_bit_cast(unsigned, f);
  unsigned r = (u + 0x7FFFu + ((u >> 16) & 1u)) >> 16;   // RNE (finite values)
  return (ushort_t)r;
}
__device__ __forceinline__ float bf2f(ushort_t h) {
  unsigned u = ((unsigned)h) << 16;
  return __builtin_bit_cast(float, u);
}

__device__ __forceinline__ void g2l16(void* lds, const void* g) {
  __builtin_amdgcn_global_load_lds(
      (const __attribute__((address_space(1))) char*)g,
      (__attribute__((address_space(3))) char*)lds, 16, 0, 0);
}

__device__ __forceinline__ f32x4 mfma16(short8 a, short8 b, f32x4 c) {
  return __builtin_amdgcn_mfma_f32_16x16x32_bf16(a, b, c, 0, 0, 0);
}
__device__ __forceinline__ f32x16 mfma32(short8 a, short8 b, f32x16 c) {
  return __builtin_amdgcn_mfma_f32_32x32x16_bf16(a, b, c, 0, 0, 0);
}

// Subtiled layouts (per batch, per 64-row tile, 32KB = 16384 ushorts), all PLAIN:
//   Q/K: [kstep16][64 row][16 us]   (wave fragment reads are contiguous 1KB)
//   V:   [kvstep4][256 d][16 us]
// tile base (ushorts): (b*NKT + tile) << 14

// ---------------- merged producer kernel ----------------
// blocks: [0,64) txt | [64,112) wt | [112,1136) tbl | [1136,1328) pad0 | [1328,3376) sig
__global__ void prep_kernel(const float* __restrict__ src, const float* __restrict__ learn,
                            const float* __restrict__ Wtq, const float* __restrict__ Wtk,
                            const float* __restrict__ Wtv,
                            const float* __restrict__ Wvq, const float* __restrict__ Wvk,
                            const float* __restrict__ Wvv,
                            ushort_t* __restrict__ Qs, ushort_t* __restrict__ Ks,
                            ushort_t* __restrict__ VTs, ushort_t* __restrict__ sigp,
                            float* __restrict__ tbl, ushort_t* __restrict__ WT,
                            float* __restrict__ loss) {
  __shared__ float shf[64 * 68];          // aliased per branch
  const int blk = blockIdx.x;
  const int tid = threadIdx.x;

  if (blk < 64) {
    // ---- txt rows: Q/K = (pos+x)W, V = xW ----
    float (*a_s)[256] = (float(*)[256])shf;
    float (*x_s)[256] = (float(*)[256])(shf + 2048);
    const int tg = blk & 3;
    const int b  = blk >> 2;
    const int c  = tid;
    #pragma unroll
    for (int t = 0; t < 8; ++t) {
      int row = tg * 8 + t;
      float x = src[((size_t)b * S_ + row) * D_ + c];
      float xe = (float)(row + 1) * (6.283185307179586f / (32.0f + 1e-6f));
      int i = c >> 1;
      float dimt = powf(10000.0f, (2.0f * (float)i) / 256.0f);
      float ang = xe / dimt;
      float pv = (c & 1) ? cosf(ang) : sinf(ang);
      x_s[t][c] = x;
      a_s[t][c] = x + pv;
    }
    __syncthreads();
    float q[8] = {0,0,0,0,0,0,0,0}, k[8] = {0,0,0,0,0,0,0,0}, v[8] = {0,0,0,0,0,0,0,0};
    for (int kk = 0; kk < 256; ++kk) {
      float wq = Wtq[(size_t)kk * 256 + c];
      float wk = Wtk[(size_t)kk * 256 + c];
      float wv = Wtv[(size_t)kk * 256 + c];
      #pragma unroll
      for (int t = 0; t < 8; ++t) {
        q[t] = fmaf(a_s[t][kk], wq, q[t]);
        k[t] = fmaf(a_s[t][kk], wk, k[t]);
        v[t] = fmaf(x_s[t][kk], wv, v[t]);
      }
    }
    #pragma unroll
    for (int t = 0; t < 8; ++t) {
      int row = tg * 8 + t;          // rows 0..31 => tile 0
      size_t base = ((size_t)(b * NKT)) << 14;
      size_t sub = (size_t)(c >> 4) * 1024 + row * 16 + (c & 15);
      Qs[base + sub] = f2bf(q[t]);
      Ks[base + sub] = f2bf(k[t]);
      VTs[base + (size_t)(row >> 4) * 4096 + c * 16 + (row & 15)] = f2bf(v[t]);
    }
  } else if (blk < 112) {
    // ---- weight transpose: WT[mat][n][k] = W[k][n] ----
    float (*t)[68] = (float(*)[68])shf;
    const int m = blk - 64;
    const int k0 = (m & 3) * 64, n0 = ((m >> 2) & 3) * 64, mt = m >> 4;
    const float* W = (mt == 0) ? Wvq : (mt == 1) ? Wvk : Wvv;
    int r = tid >> 4, cq = (tid & 15) * 4;
    #pragma unroll
    for (int mm = 0; mm < 4; ++mm) {
      int k = mm * 16 + r;
      float4 v = *(const float4*)(W + (size_t)(k0 + k) * 256 + n0 + cq);
      t[k][cq] = v.x; t[k][cq + 1] = v.y; t[k][cq + 2] = v.z; t[k][cq + 3] = v.w;
    }
    __syncthreads();
    #pragma unroll
    for (int mm = 0; mm < 4; ++mm) {
      int n = mm * 16 + r;
      short4v h;
      h[0] = (short)f2bf(t[cq + 0][n]);
      h[1] = (short)f2bf(t[cq + 1][n]);
      h[2] = (short)f2bf(t[cq + 2][n]);
      h[3] = (short)f2bf(t[cq + 3][n]);
      *(short4v*)(WT + ((size_t)mt * D_ + n0 + n) * D_ + k0 + cq) = h;
    }
  } else if (blk < 1136) {
    // ---- xpos table ----
    int idx = (blk - 112) * 256 + tid;
    int n = idx >> 7, i = idx & 127;
    float invf = powf(10000.0f, -(float)i / 128.0f);
    float ang = (float)n * invf;
    float s, co;
    sincosf(ang, &s, &co);
    float sv = ((float)(2 * i) + 102.4f) / 358.4f;
    float sc = powf(sv, (float)n / 512.0f);
    float4 r;
    r.x = co * sc; r.y = s * sc; r.z = co / sc; r.w = s / sc;
    *(float4*)(tbl + (size_t)idx * 4) = r;
  } else if (blk < 1328) {
    // ---- zero-fill padding (tile 32: Q/K rows 32..63, V kvsteps 2..3) ----
    int i = (blk - 1136) * 256 + tid;           // 49152 total
    short8 z = {0, 0, 0, 0, 0, 0, 0, 0};
    int sec = i >> 14;
    int j = i & 16383;
    int bb = j >> 10;
    int rem = j & 1023;
    size_t base = ((size_t)(bb * NKT + 32)) << 14;
    if (sec == 0) {
      int kstep = rem >> 6, ch = rem & 63;
      *(short8*)(Qs + base + kstep * 1024 + 512 + ch * 8) = z;
    } else if (sec == 1) {
      int kstep = rem >> 6, ch = rem & 63;
      *(short8*)(Ks + base + kstep * 1024 + 512 + ch * 8) = z;
    } else {
      *(short8*)(VTs + base + 8192 + rem * 8) = z;
    }
  } else {
    // ---- sigmoid mask (row-major bf16) + sparsity loss ----
    float* red = shf;
    const int base = ((blk - 1328) * 256 + tid) * 8;
    float4 v0 = *(const float4*)(learn + base);
    float4 v1 = *(const float4*)(learn + base + 4);
    float vals[8] = {v0.x, v0.y, v0.z, v0.w, v1.x, v1.y, v1.z, v1.w};
    float acc = 0.f;
    short8 sh;
    #pragma unroll
    for (int j = 0; j < 8; ++j) {
      int idx = base + j;
      float s = 1.0f / (1.0f + expf(-vals[j]));
      sh[j] = (short)f2bf(s);
      int rr = idx >> 11, cc = idx & 2047;
      if (rr != cc) acc += s;
    }
    *(short8*)(sigp + base) = sh;
    red[tid] = acc;
    __syncthreads();
    #pragma unroll
    for (int st = 128; st > 0; st >>= 1) {
      if (tid < st) red[tid] += red[tid + st];
      __syncthreads();
    }
    if (tid == 0) atomicAdd(loss, red[0] * (1.0f / 4194304.0f));
  }
}

// ---------------- src vid rows -> bf16 ----------------
__global__ void cvt_kernel(const float* __restrict__ src, ushort_t* __restrict__ srcb) {
  int i = blockIdx.x * 256 + threadIdx.x;
  int b = i >> 16;
  int rem = i & 65535;
  int row = rem >> 5, c8 = (rem & 31) * 8;
  const float* p = src + ((size_t)b * S_ + TXT + row) * D_ + c8;
  float4 v0 = *(const float4*)p;
  float4 v1 = *(const float4*)(p + 4);
  short8 h;
  h[0] = (short)f2bf(v0.x); h[1] = (short)f2bf(v0.y); h[2] = (short)f2bf(v0.z); h[3] = (short)f2bf(v0.w);
  h[4] = (short)f2bf(v1.x); h[5] = (short)f2bf(v1.y); h[6] = (short)f2bf(v1.z); h[7] = (short)f2bf(v1.w);
  *(short8*)(srcb + ((size_t)b * VID + row) * D_ + c8) = h;
}

// ---------------- vid projection GEMM (per-tile grid, +xpos epilogue) ----------------
// MODE 0: A from f32 src (cvt in-kernel).  MODE 1: A via g2l16 from bf16 srcb (pre-XOR'd source).
template <int MODE>
__global__ __launch_bounds__(256, 2) void vid_gemm(
    const float* __restrict__ src, const ushort_t* __restrict__ srcb,
    const ushort_t* __restrict__ WT, const float* __restrict__ tbl,
    ushort_t* __restrict__ Qs, ushort_t* __restrict__ Ks, ushort_t* __restrict__ VTs) {
  __shared__ __align__(16) ushort_t ldsA[64 * 64];
  __shared__ __align__(16) ushort_t ldsB[64 * 64];

  const int rt = blockIdx.x;
  const int b  = blockIdx.y;
  const int ct = blockIdx.z;
  const int nt = ct >> 2;
  const int n0 = (ct & 3) * 64;
  const int tid = threadIdx.x;
  const int wv = tid >> 6, lane = tid & 63, l15 = lane & 15, l4 = lane >> 4;

  f32x4 acc[4];
  #pragma unroll
  for (int t2 = 0; t2 < 4; ++t2) { acc[t2][0] = 0.f; acc[t2][1] = 0.f; acc[t2][2] = 0.f; acc[t2][3] = 0.f; }

  for (int kk = 0; kk < 256; kk += 64) {
    if (MODE == 1) {
      #pragma unroll
      for (int m = 0; m < 2; ++m) {
        int p = (m * 256 + tid) * 16;
        int r = p >> 7;
        int cb = (p & 127) ^ ((r & 7) << 4);
        g2l16((char*)ldsA + p,
              (const char*)(srcb + ((size_t)b * VID + rt * 64 + r) * D_ + kk) + cb);
      }
    } else {
      #pragma unroll
      for (int m = 0; m < 4; ++m) {
        int q = m * 256 + tid;
        int r = q >> 4;
        int kc = (q & 15) * 4;
        const float4 v = *(const float4*)(src + ((size_t)b * S_ + TXT + rt * 64 + r) * D_ + kk + kc);
        short4v h;
        h[0] = (short)f2bf(v.x); h[1] = (short)f2bf(v.y);
        h[2] = (short)f2bf(v.z); h[3] = (short)f2bf(v.w);
        int off = ((r << 7) + (kc << 1)) ^ ((r & 7) << 4);
        *(short4v*)((char*)ldsA + off) = h;
      }
    }
    #pragma unroll
    for (int m = 0; m < 2; ++m) {
      int p = (m * 256 + tid) * 16;
      int nl = p >> 7;
      int c = (p & 127) ^ ((nl & 7) << 4);
      g2l16((char*)ldsB + p, (const char*)(WT + ((size_t)nt * D_ + n0 + nl) * D_ + kk) + c);
    }
    __syncthreads();
    #pragma unroll
    for (int ks = 0; ks < 2; ++ks) {
      int ar = wv * 16 + l15;
      int aoff = ((ar << 7) + ((ks * 32 + l4 * 8) << 1)) ^ ((ar & 7) << 4);
      short8 av = *(const short8*)((const char*)ldsA + aoff);
      #pragma unroll
      for (int t2 = 0; t2 < 4; ++t2) {
        int nl = t2 * 16 + l15;
        int boff = ((nl << 7) + ((ks * 32 + l4 * 8) << 1)) ^ ((nl & 7) << 4);
        short8 bv = *(const short8*)((const char*)ldsB + boff);
        acc[t2] = mfma16(av, bv, acc[t2]);
      }
    }
    __syncthreads();
  }

  const int rowl = wv * 16 + l4 * 4;
  if (nt < 2) {
    #pragma unroll
    for (int t2 = 0; t2 < 4; ++t2) {
      int c = n0 + t2 * 16 + l15;
      #pragma unroll
      for (int r = 0; r < 4; ++r) {
        int n = rt * 64 + rowl + r;
        float x = acc[t2][r];
        float xp = __shfl_xor(x, 1);
        const float4 tb = *(const float4*)(tbl + ((size_t)n * 128 + (c >> 1)) * 4);
        float cs = (nt == 0) ? tb.x : tb.z;
        float ss = (nt == 0) ? tb.y : tb.w;
        float val = (c & 1) ? fmaf(x, cs, xp * ss) : fmaf(x, cs, -xp * ss);
        int rowg = TXT + n;
        size_t idx = (((size_t)(b * NKT + (rowg >> 6))) << 14)
                   + (size_t)(c >> 4) * 1024 + (rowg & 63) * 16 + (c & 15);
        if (nt == 0) Qs[idx] = f2bf(val);
        else         Ks[idx] = f2bf(val);
      }
    }
  } else {
    #pragma unroll
    for (int t2 = 0; t2 < 4; ++t2)
      #pragma unroll
      for (int r = 0; r < 4; ++r) {
        int rr = rowl + r;
        int cc = t2 * 16 + l15;
        int off = ((rr << 7) + (cc << 1)) ^ ((rr & 7) << 4);
        *(ushort_t*)((char*)ldsA + off) = f2bf(acc[t2][r]);
      }
    __syncthreads();
    int n = tid >> 2;
    int rc = (tid & 3) * 16;
    short8 o0, o1;
    #pragma unroll
    for (int j = 0; j < 8; ++j) {
      int rr = rc + j;
      int off = ((rr << 7) + (n << 1)) ^ ((rr & 7) << 4);
      o0[j] = *(const short*)((const char*)ldsA + off);
    }
    #pragma unroll
    for (int j = 0; j < 8; ++j) {
      int rr = rc + 8 + j;
      int off = ((rr << 7) + (n << 1)) ^ ((rr & 7) << 4);
      o1[j] = *(const short*)((const char*)ldsA + off);
    }
    int d = n0 + n;
    int kvg0 = TXT + rt * 64 + rc;
    size_t base = (((size_t)(b * NKT + (kvg0 >> 6))) << 14) + ((kvg0 >> 4) & 3) * 4096 + d * 16;
    *(short8*)(VTs + base) = o0;
    *(short8*)(VTs + base + 8) = o1;
  }
}

// ---------------- fused masked attention v14: 40KB LDS, V direct, (256,2) ----------------
// r13 structure with the launch bound reverted to the known-good (256,2): r13's (256,4)
// capped VGPR at 64 -> 1.4GB spill (same failure as r7). With ~120 VGPR and 40KB LDS the
// HW limits give 4 blocks/CU (16 waves) without any cap: LDS 160/40=4, VGPR 120<128.
__global__ __launch_bounds__(256, 2) void attn_kernel(
    const ushort_t* __restrict__ Qs, const ushort_t* __restrict__ Ks,
    const ushort_t* __restrict__ VTs, const ushort_t* __restrict__ sigp,
    float* __restrict__ out) {
  __shared__ __align__(16) ushort_t Kb[16384];      // 32KB  K(t)
  __shared__ __align__(16) ushort_t Pb[4096];       // 8KB   [32 rows][256B], XOR swz

  const int kblk = blockIdx.x;                      // 0..511
  const int bs = (kblk & 7) * 64 + (kblk >> 3);     // XCD-chunked bijective swizzle
  int g = bs * 34 + (bs >> 5);
  const int gend = (bs + 1) * 34 + ((bs + 1) >> 5);

  const int tid = threadIdx.x;
  const int wid = tid >> 6, lane = tid & 63;
  const int l31 = lane & 31, l5 = lane >> 5;
  const int qh = wid >> 1, kh = wid & 1;            // QK quarter
  const int d0 = wid * 64;                          // PV d-slice
  const int qloc = qh * 32 + l31;
  const int pkey = (l31 & 15) << 4;                 // 4-bit involutive XOR key

  int b = g / 1089, rem = g - b * 1089, qt = rem / 33, kvt = rem - qt * 33;

  short8 qf[16];
  int2 mq[4];

  auto ldq = [&](int bb, int qq) {
    const ushort_t* qb = Qs + (((size_t)(bb * NKT + qq)) << 14) + qloc * 16 + l5 * 8;
    #pragma unroll
    for (int ks = 0; ks < 16; ++ks) qf[ks] = *(const short8*)(qb + ks * 1024);
  };
  auto ldmask = [&](int qq, int tt) {
    int q = qq * 64 + qloc;
    int qc = q - TXT; qc = qc < 0 ? 0 : (qc > 2047 ? 2047 : qc);
    int kvp = tt * 64 + kh * 32 - TXT;
    int kvc = (kvp >= 0 && kvp <= 2016) ? kvp : 0;
    const char* mrow = (const char*)(sigp + (size_t)qc * 2048 + kvc) + l5 * 8;
    #pragma unroll
    for (int t = 0; t < 4; ++t) mq[t] = *(const int2*)(mrow + 16 * t);
  };
  auto stageK = [&](int bb, int tt) {
    const char* src = (const char*)Ks + (((size_t)(bb * NKT + tt)) << 15);
    #pragma unroll
    for (int m = 0; m < 8; ++m) { int s2 = m * 256 + tid; g2l16((char*)Kb + s2 * 16, src + s2 * 16); }
  };

  f32x16 oacc[2][2];
  #pragma unroll
  for (int i2 = 0; i2 < 2; ++i2)
    #pragma unroll
    for (int j2 = 0; j2 < 2; ++j2)
      #pragma unroll
      for (int r = 0; r < 16; ++r) oacc[i2][j2][r] = 0.f;

  auto flushO = [&](int bb, int qq) {
    #pragma unroll
    for (int qg2 = 0; qg2 < 2; ++qg2)
      #pragma unroll
      for (int dg = 0; dg < 2; ++dg)
        #pragma unroll
        for (int r = 0; r < 16; ++r) {
          int qg = qq * 64 + qg2 * 32 + (r & 3) + 8 * (r >> 2) + 4 * l5;
          int dd = d0 + dg * 32 + l31;
          if (qg < S_)
            unsafeAtomicAdd(&out[((size_t)bb * S_ + qg) * D_ + dd], oacc[qg2][dg][r]);
          oacc[qg2][dg][r] = 0.f;
        }
  };

  // ---- prologue ----
  stageK(b, kvt);
  ldmask(qt, kvt);
  ldq(b, qt);
  asm volatile("s_waitcnt vmcnt(0)" ::: "memory");
  __builtin_amdgcn_sched_barrier(0);
  __builtin_amdgcn_s_barrier();
  __builtin_amdgcn_sched_barrier(0);

  while (g < gend) {
    int gn = (g + 1 < GTOT) ? g + 1 : GTOT - 1;
    int nb = gn / 1089, nrem = gn - nb * 1089, nqt = nrem / 33, nkvt = nrem - nqt * 33;

    // ---- QK (S^T = K . Q^T): 2 independent chains from LDS ----
    f32x16 s0, s1;
    #pragma unroll
    for (int r = 0; r < 16; ++r) { s0[r] = 0.f; s1[r] = 0.f; }
    const int arow = (kh * 32 + l31) * 32 + l5 * 16;
    __builtin_amdgcn_s_setprio(1);
    #pragma unroll
    for (int ks = 0; ks < 8; ++ks) {
      short8 ka = *(const short8*)((const char*)Kb + ks * 2048 + arow);
      short8 kc = *(const short8*)((const char*)Kb + (ks + 8) * 2048 + arow);
      s0 = mfma32(ka, qf[ks], s0);
      s1 = mfma32(kc, qf[ks + 8], s1);
    }
    __builtin_amdgcn_s_setprio(0);

    // ---- mask + pack P (bf16) -> Pb (row = q&31, 256B rows, 4-bit XOR) ----
    {
      int q = qt * 64 + qloc;
      bool qv = (q >= TXT) && (q < S_);
      int kvp = kvt * 64 + kh * 32 - TXT;
      bool kvv = (kvp >= 0 && kvp <= 2016);
      bool ok = qv && kvv;
      #pragma unroll
      for (int t = 0; t < 4; ++t) {
        unsigned w0p, w1p;
        {
          unsigned w = (unsigned)mq[t].x;
          float m0 = ok ? bf2f((ushort_t)(w & 0xFFFFu)) : 1.0f;
          float m1 = ok ? bf2f((ushort_t)(w >> 16)) : 1.0f;
          int r = 4 * t;
          float p0 = (s0[r] + s1[r]) * m0;
          float p1 = (s0[r + 1] + s1[r + 1]) * m1;
          asm("v_cvt_pk_bf16_f32 %0, %1, %2" : "=v"(w0p) : "v"(p0), "v"(p1));
        }
        {
          unsigned w = (unsigned)mq[t].y;
          float m0 = ok ? bf2f((ushort_t)(w & 0xFFFFu)) : 1.0f;
          float m1 = ok ? bf2f((ushort_t)(w >> 16)) : 1.0f;
          int r = 4 * t + 2;
          float p0 = (s0[r] + s1[r]) * m0;
          float p1 = (s0[r + 1] + s1[r + 1]) * m1;
          asm("v_cvt_pk_bf16_f32 %0, %1, %2" : "=v"(w1p) : "v"(p0), "v"(p1));
        }
        int off = (l31 << 8) + (((qh << 7) + (kh << 6) + (t << 4) + (l5 << 3)) ^ pkey);
        *(uint2*)((char*)Pb + off) = make_uint2(w0p, w1p);
      }
    }

    asm volatile("s_waitcnt lgkmcnt(0)" ::: "memory");   // Kb reads + Pb writes done
    __builtin_amdgcn_sched_barrier(0);
    __builtin_amdgcn_s_barrier();          // barrier 1
    __builtin_amdgcn_sched_barrier(0);

    stageK(nb, nkvt);                      // K(t+1) into freed Kb
    __builtin_amdgcn_sched_barrier(0);

    // ---- PV: O[64q x 64d-slice] += P * V, V DIRECT from global ----
    const ushort_t* vb = VTs + (((size_t)(b * NKT + kvt)) << 14) + (size_t)d0 * 16 + l5 * 8;
    __builtin_amdgcn_s_setprio(1);
    #pragma unroll
    for (int ks = 0; ks < 4; ++ks) {
      short8 vf0 = *(const short8*)(vb + ks * 4096 + l31 * 16);
      short8 vf1 = *(const short8*)(vb + ks * 4096 + (l31 + 32) * 16);
      int p0 = (l31 << 8) + ((ks * 32 + l5 * 16) ^ pkey);
      int p1 = (l31 << 8) + ((128 + ks * 32 + l5 * 16) ^ pkey);
      short8 pf0 = *(const short8*)((const char*)Pb + p0);
      short8 pf1 = *(const short8*)((const char*)Pb + p1);
      oacc[0][0] = mfma32(pf0, vf0, oacc[0][0]);
      oacc[0][1] = mfma32(pf0, vf1, oacc[0][1]);
      oacc[1][0] = mfma32(pf1, vf0, oacc[1][0]);
      oacc[1][1] = mfma32(pf1, vf1, oacc[1][1]);
    }
    __builtin_amdgcn_s_setprio(0);
    asm volatile("s_waitcnt lgkmcnt(0)" ::: "memory");   // Pb reads retired
    __builtin_amdgcn_sched_barrier(0);

    // ---- tail: masks(t+1); ensure K(t+1) landed; flush at q boundaries ----
    ldmask(nqt, nkvt);                                   // 4 loads (newest)
    __builtin_amdgcn_sched_barrier(0);
    asm volatile("s_waitcnt vmcnt(4)" ::: "memory");     // K8 done; masks flying
    __builtin_amdgcn_sched_barrier(0);
    const bool qchange = (nqt != qt || nb != b);
    if (qchange) {                          // q-tile boundary (block-uniform)
      flushO(b, qt);
      ldq(nb, nqt);
    }
    __builtin_amdgcn_sched_barrier(0);
    __builtin_amdgcn_s_barrier();          // barrier 2: K(t+1)/P ready block-wide
    __builtin_amdgcn_sched_barrier(0);

    b = nb; qt = nqt; kvt = nkvt; ++g;
  }

  flushO(b, qt);
}

extern "C" void kernel_launch(void* const* d_in, const int* in_sizes, int n_in,
                              void* d_out, int out_size, void* d_ws, size_t ws_size,
                              hipStream_t stream) {
  (void)in_sizes; (void)n_in;
  const float* src   = (const float*)d_in[0];
  const float* learn = (const float*)d_in[1];
  const float* Wtq = (const float*)d_in[2];
  const float* Wtk = (const float*)d_in[3];
  const float* Wtv = (const float*)d_in[4];
  const float* Wvq = (const float*)d_in[5];
  const float* Wvk = (const float*)d_in[6];
  const float* Wvv = (const float*)d_in[7];
  float* out = (float*)d_out;

  char* ws = (char*)d_ws;
  const size_t QKV_ONE  = (size_t)B_ * SP * D_ * 2;
  const size_t QP_OFF   = 0;
  const size_t KS_OFF   = QP_OFF + QKV_ONE;
  const size_t VT_OFF   = KS_OFF + QKV_ONE;
  const size_t SIG_OFF  = VT_OFF + QKV_ONE;
  const size_t TBL_OFF  = SIG_OFF + (size_t)VID * VID * 2;
  const size_t WT_OFF   = TBL_OFF + (size_t)VID * 128 * 4 * sizeof(float);
  const size_t SRCB_OFF = WT_OFF + (size_t)3 * D_ * D_ * 2;
  const size_t NEED_SRCB = SRCB_OFF + (size_t)B_ * VID * D_ * 2;

  ushort_t* Qs   = (ushort_t*)(ws + QP_OFF);
  ushort_t* Ks   = (ushort_t*)(ws + KS_OFF);
  ushort_t* VTs  = (ushort_t*)(ws + VT_OFF);
  ushort_t* sigp = (ushort_t*)(ws + SIG_OFF);
  float*    tbl  = (float*)(ws + TBL_OFF);
  ushort_t* WT   = (ushort_t*)(ws + WT_OFF);
  ushort_t* srcb = (ushort_t*)(ws + SRCB_OFF);
  float*    loss = out + (size_t)B_ * S_ * D_;

  hipMemsetAsync(d_out, 0, (size_t)out_size * sizeof(float), stream);  // atomics + loss
  prep_kernel<<<3376, 256, 0, stream>>>(src, learn, Wtq, Wtk, Wtv, Wvq, Wvk, Wvv,
                                        Qs, Ks, VTs, sigp, tbl, WT, loss);
  if (ws_size >= NEED_SRCB) {
    cvt_kernel<<<4096, 256, 0, stream>>>(src, srcb);
    vid_gemm<1><<<dim3(32, B_, 12), 256, 0, stream>>>(src, srcb, WT, tbl, Qs, Ks, VTs);
  } else {
    vid_gemm<0><<<dim3(32, B_, 12), 256, 0, stream>>>(src, srcb, WT, tbl, Qs, Ks, VTs);
  }
  attn_kernel<<<dim3(512), 256, 0, stream>>>(Qs, Ks, VTs, sigp, out);
}

// Round 15
// 289.790 us; speedup vs baseline: 2.2444x; 1.0032x over previous
//
#include <hip/hip_runtime.h>

#define B_   16
#define TXT  32
#define VID  2048
#define D_   256
#define S_   2080
#define SP   2176   // padded sequence rows (34 tiles of 64)
#define NKT  34     // tiles (64 rows each) in Q/K/V subtiled layouts
#define GTOT 17424  // 16 b * 33 qt * 33 kv global iterations

typedef unsigned short ushort_t;
typedef __attribute__((ext_vector_type(8))) short short8;
typedef __attribute__((ext_vector_type(4))) short short4v;
typedef __attribute__((ext_vector_type(4))) float f32x4;
typedef __attribute__((ext_vector_type(16))) float f32x16;

__device__ __forceinline__ ushort_t f2bf(float f) {
  unsigned u = __builtin_bit_cast(unsigned, f);
  unsigned r = (u + 0x7FFFu + ((u >> 16) & 1u)) >> 16;   // RNE (finite values)
  return (ushort_t)r;
}
__device__ __forceinline__ float bf2f(ushort_t h) {
  unsigned u = ((unsigned)h) << 16;
  return __builtin_bit_cast(float, u);
}

__device__ __forceinline__ void g2l16(void* lds, const void* g) {
  __builtin_amdgcn_global_load_lds(
      (const __attribute__((address_space(1))) char*)g,
      (__attribute__((address_space(3))) char*)lds, 16, 0, 0);
}

__device__ __forceinline__ f32x4 mfma16(short8 a, short8 b, f32x4 c) {
  return __builtin_amdgcn_mfma_f32_16x16x32_bf16(a, b, c, 0, 0, 0);
}
__device__ __forceinline__ f32x16 mfma32(short8 a, short8 b, f32x16 c) {
  return __builtin_amdgcn_mfma_f32_32x32x16_bf16(a, b, c, 0, 0, 0);
}

// Subtiled layouts (per batch, per 64-row tile, 32KB = 16384 ushorts), all PLAIN:
//   Q/K: [kstep16][64 row][16 us]   (wave fragment reads are contiguous 1KB)
//   V:   [kvstep4][256 d][16 us]
// tile base (ushorts): (b*NKT + tile) << 14

// ---------------- merged producer kernel ----------------
// blocks: [0,64) txt | [64,112) wt | [112,1136) tbl | [1136,1328) pad0 | [1328,3376) sig
__global__ void prep_kernel(const float* __restrict__ src, const float* __restrict__ learn,
                            const float* __restrict__ Wtq, const float* __restrict__ Wtk,
                            const float* __restrict__ Wtv,
                            const float* __restrict__ Wvq, const float* __restrict__ Wvk,
                            const float* __restrict__ Wvv,
                            ushort_t* __restrict__ Qs, ushort_t* __restrict__ Ks,
                            ushort_t* __restrict__ VTs, ushort_t* __restrict__ sigp,
                            float* __restrict__ tbl, ushort_t* __restrict__ WT,
                            float* __restrict__ loss) {
  __shared__ float shf[64 * 68];          // aliased per branch
  const int blk = blockIdx.x;
  const int tid = threadIdx.x;

  if (blk < 64) {
    // ---- txt rows: Q/K = (pos+x)W, V = xW ----
    float (*a_s)[256] = (float(*)[256])shf;
    float (*x_s)[256] = (float(*)[256])(shf + 2048);
    const int tg = blk & 3;
    const int b  = blk >> 2;
    const int c  = tid;
    #pragma unroll
    for (int t = 0; t < 8; ++t) {
      int row = tg * 8 + t;
      float x = src[((size_t)b * S_ + row) * D_ + c];
      float xe = (float)(row + 1) * (6.283185307179586f / (32.0f + 1e-6f));
      int i = c >> 1;
      float dimt = powf(10000.0f, (2.0f * (float)i) / 256.0f);
      float ang = xe / dimt;
      float pv = (c & 1) ? cosf(ang) : sinf(ang);
      x_s[t][c] = x;
      a_s[t][c] = x + pv;
    }
    __syncthreads();
    float q[8] = {0,0,0,0,0,0,0,0}, k[8] = {0,0,0,0,0,0,0,0}, v[8] = {0,0,0,0,0,0,0,0};
    for (int kk = 0; kk < 256; ++kk) {
      float wq = Wtq[(size_t)kk * 256 + c];
      float wk = Wtk[(size_t)kk * 256 + c];
      float wv = Wtv[(size_t)kk * 256 + c];
      #pragma unroll
      for (int t = 0; t < 8; ++t) {
        q[t] = fmaf(a_s[t][kk], wq, q[t]);
        k[t] = fmaf(a_s[t][kk], wk, k[t]);
        v[t] = fmaf(x_s[t][kk], wv, v[t]);
      }
    }
    #pragma unroll
    for (int t = 0; t < 8; ++t) {
      int row = tg * 8 + t;          // rows 0..31 => tile 0
      size_t base = ((size_t)(b * NKT)) << 14;
      size_t sub = (size_t)(c >> 4) * 1024 + row * 16 + (c & 15);
      Qs[base + sub] = f2bf(q[t]);
      Ks[base + sub] = f2bf(k[t]);
      VTs[base + (size_t)(row >> 4) * 4096 + c * 16 + (row & 15)] = f2bf(v[t]);
    }
  } else if (blk < 112) {
    // ---- weight transpose: WT[mat][n][k] = W[k][n] ----
    float (*t)[68] = (float(*)[68])shf;
    const int m = blk - 64;
    const int k0 = (m & 3) * 64, n0 = ((m >> 2) & 3) * 64, mt = m >> 4;
    const float* W = (mt == 0) ? Wvq : (mt == 1) ? Wvk : Wvv;
    int r = tid >> 4, cq = (tid & 15) * 4;
    #pragma unroll
    for (int mm = 0; mm < 4; ++mm) {
      int k = mm * 16 + r;
      float4 v = *(const float4*)(W + (size_t)(k0 + k) * 256 + n0 + cq);
      t[k][cq] = v.x; t[k][cq + 1] = v.y; t[k][cq + 2] = v.z; t[k][cq + 3] = v.w;
    }
    __syncthreads();
    #pragma unroll
    for (int mm = 0; mm < 4; ++mm) {
      int n = mm * 16 + r;
      short4v h;
      h[0] = (short)f2bf(t[cq + 0][n]);
      h[1] = (short)f2bf(t[cq + 1][n]);
      h[2] = (short)f2bf(t[cq + 2][n]);
      h[3] = (short)f2bf(t[cq + 3][n]);
      *(short4v*)(WT + ((size_t)mt * D_ + n0 + n) * D_ + k0 + cq) = h;
    }
  } else if (blk < 1136) {
    // ---- xpos table ----
    int idx = (blk - 112) * 256 + tid;
    int n = idx >> 7, i = idx & 127;
    float invf = powf(10000.0f, -(float)i / 128.0f);
    float ang = (float)n * invf;
    float s, co;
    sincosf(ang, &s, &co);
    float sv = ((float)(2 * i) + 102.4f) / 358.4f;
    float sc = powf(sv, (float)n / 512.0f);
    float4 r;
    r.x = co * sc; r.y = s * sc; r.z = co / sc; r.w = s / sc;
    *(float4*)(tbl + (size_t)idx * 4) = r;
  } else if (blk < 1328) {
    // ---- zero-fill padding (tile 32: Q/K rows 32..63, V kvsteps 2..3) ----
    int i = (blk - 1136) * 256 + tid;           // 49152 total
    short8 z = {0, 0, 0, 0, 0, 0, 0, 0};
    int sec = i >> 14;
    int j = i & 16383;
    int bb = j >> 10;
    int rem = j & 1023;
    size_t base = ((size_t)(bb * NKT + 32)) << 14;
    if (sec == 0) {
      int kstep = rem >> 6, ch = rem & 63;
      *(short8*)(Qs + base + kstep * 1024 + 512 + ch * 8) = z;
    } else if (sec == 1) {
      int kstep = rem >> 6, ch = rem & 63;
      *(short8*)(Ks + base + kstep * 1024 + 512 + ch * 8) = z;
    } else {
      *(short8*)(VTs + base + 8192 + rem * 8) = z;
    }
  } else {
    // ---- sigmoid mask (row-major bf16) + sparsity loss ----
    float* red = shf;
    const int base = ((blk - 1328) * 256 + tid) * 8;
    float4 v0 = *(const float4*)(learn + base);
    float4 v1 = *(const float4*)(learn + base + 4);
    float vals[8] = {v0.x, v0.y, v0.z, v0.w, v1.x, v1.y, v1.z, v1.w};
    float acc = 0.f;
    short8 sh;
    #pragma unroll
    for (int j = 0; j < 8; ++j) {
      int idx = base + j;
      float s = 1.0f / (1.0f + expf(-vals[j]));
      sh[j] = (short)f2bf(s);
      int rr = idx >> 11, cc = idx & 2047;
      if (rr != cc) acc += s;
    }
    *(short8*)(sigp + base) = sh;
    red[tid] = acc;
    __syncthreads();
    #pragma unroll
    for (int st = 128; st > 0; st >>= 1) {
      if (tid < st) red[tid] += red[tid + st];
      __syncthreads();
    }
    if (tid == 0) atomicAdd(loss, red[0] * (1.0f / 4194304.0f));
  }
}

// ---------------- src vid rows -> bf16 ----------------
__global__ void cvt_kernel(const float* __restrict__ src, ushort_t* __restrict__ srcb) {
  int i = blockIdx.x * 256 + threadIdx.x;
  int b = i >> 16;
  int rem = i & 65535;
  int row = rem >> 5, c8 = (rem & 31) * 8;
  const float* p = src + ((size_t)b * S_ + TXT + row) * D_ + c8;
  float4 v0 = *(const float4*)p;
  float4 v1 = *(const float4*)(p + 4);
  short8 h;
  h[0] = (short)f2bf(v0.x); h[1] = (short)f2bf(v0.y); h[2] = (short)f2bf(v0.z); h[3] = (short)f2bf(v0.w);
  h[4] = (short)f2bf(v1.x); h[5] = (short)f2bf(v1.y); h[6] = (short)f2bf(v1.z); h[7] = (short)f2bf(v1.w);
  *(short8*)(srcb + ((size_t)b * VID + row) * D_ + c8) = h;
}

// ---------------- vid projection GEMM (per-tile grid, +xpos epilogue) ----------------
// MODE 0: A from f32 src (cvt in-kernel).  MODE 1: A via g2l16 from bf16 srcb (pre-XOR'd source).
template <int MODE>
__global__ __launch_bounds__(256, 2) void vid_gemm(
    const float* __restrict__ src, const ushort_t* __restrict__ srcb,
    const ushort_t* __restrict__ WT, const float* __restrict__ tbl,
    ushort_t* __restrict__ Qs, ushort_t* __restrict__ Ks, ushort_t* __restrict__ VTs) {
  __shared__ __align__(16) ushort_t ldsA[64 * 64];
  __shared__ __align__(16) ushort_t ldsB[64 * 64];

  const int rt = blockIdx.x;
  const int b  = blockIdx.y;
  const int ct = blockIdx.z;
  const int nt = ct >> 2;
  const int n0 = (ct & 3) * 64;
  const int tid = threadIdx.x;
  const int wv = tid >> 6, lane = tid & 63, l15 = lane & 15, l4 = lane >> 4;

  f32x4 acc[4];
  #pragma unroll
  for (int t2 = 0; t2 < 4; ++t2) { acc[t2][0] = 0.f; acc[t2][1] = 0.f; acc[t2][2] = 0.f; acc[t2][3] = 0.f; }

  for (int kk = 0; kk < 256; kk += 64) {
    if (MODE == 1) {
      #pragma unroll
      for (int m = 0; m < 2; ++m) {
        int p = (m * 256 + tid) * 16;
        int r = p >> 7;
        int cb = (p & 127) ^ ((r & 7) << 4);
        g2l16((char*)ldsA + p,
              (const char*)(srcb + ((size_t)b * VID + rt * 64 + r) * D_ + kk) + cb);
      }
    } else {
      #pragma unroll
      for (int m = 0; m < 4; ++m) {
        int q = m * 256 + tid;
        int r = q >> 4;
        int kc = (q & 15) * 4;
        const float4 v = *(const float4*)(src + ((size_t)b * S_ + TXT + rt * 64 + r) * D_ + kk + kc);
        short4v h;
        h[0] = (short)f2bf(v.x); h[1] = (short)f2bf(v.y);
        h[2] = (short)f2bf(v.z); h[3] = (short)f2bf(v.w);
        int off = ((r << 7) + (kc << 1)) ^ ((r & 7) << 4);
        *(short4v*)((char*)ldsA + off) = h;
      }
    }
    #pragma unroll
    for (int m = 0; m < 2; ++m) {
      int p = (m * 256 + tid) * 16;
      int nl = p >> 7;
      int c = (p & 127) ^ ((nl & 7) << 4);
      g2l16((char*)ldsB + p, (const char*)(WT + ((size_t)nt * D_ + n0 + nl) * D_ + kk) + c);
    }
    __syncthreads();
    #pragma unroll
    for (int ks = 0; ks < 2; ++ks) {
      int ar = wv * 16 + l15;
      int aoff = ((ar << 7) + ((ks * 32 + l4 * 8) << 1)) ^ ((ar & 7) << 4);
      short8 av = *(const short8*)((const char*)ldsA + aoff);
      #pragma unroll
      for (int t2 = 0; t2 < 4; ++t2) {
        int nl = t2 * 16 + l15;
        int boff = ((nl << 7) + ((ks * 32 + l4 * 8) << 1)) ^ ((nl & 7) << 4);
        short8 bv = *(const short8*)((const char*)ldsB + boff);
        acc[t2] = mfma16(av, bv, acc[t2]);
      }
    }
    __syncthreads();
  }

  const int rowl = wv * 16 + l4 * 4;
  if (nt < 2) {
    #pragma unroll
    for (int t2 = 0; t2 < 4; ++t2) {
      int c = n0 + t2 * 16 + l15;
      #pragma unroll
      for (int r = 0; r < 4; ++r) {
        int n = rt * 64 + rowl + r;
        float x = acc[t2][r];
        float xp = __shfl_xor(x, 1);
        const float4 tb = *(const float4*)(tbl + ((size_t)n * 128 + (c >> 1)) * 4);
        float cs = (nt == 0) ? tb.x : tb.z;
        float ss = (nt == 0) ? tb.y : tb.w;
        float val = (c & 1) ? fmaf(x, cs, xp * ss) : fmaf(x, cs, -xp * ss);
        int rowg = TXT + n;
        size_t idx = (((size_t)(b * NKT + (rowg >> 6))) << 14)
                   + (size_t)(c >> 4) * 1024 + (rowg & 63) * 16 + (c & 15);
        if (nt == 0) Qs[idx] = f2bf(val);
        else         Ks[idx] = f2bf(val);
      }
    }
  } else {
    #pragma unroll
    for (int t2 = 0; t2 < 4; ++t2)
      #pragma unroll
      for (int r = 0; r < 4; ++r) {
        int rr = rowl + r;
        int cc = t2 * 16 + l15;
        int off = ((rr << 7) + (cc << 1)) ^ ((rr & 7) << 4);
        *(ushort_t*)((char*)ldsA + off) = f2bf(acc[t2][r]);
      }
    __syncthreads();
    int n = tid >> 2;
    int rc = (tid & 3) * 16;
    short8 o0, o1;
    #pragma unroll
    for (int j = 0; j < 8; ++j) {
      int rr = rc + j;
      int off = ((rr << 7) + (n << 1)) ^ ((rr & 7) << 4);
      o0[j] = *(const short*)((const char*)ldsA + off);
    }
    #pragma unroll
    for (int j = 0; j < 8; ++j) {
      int rr = rc + 8 + j;
      int off = ((rr << 7) + (n << 1)) ^ ((rr & 7) << 4);
      o1[j] = *(const short*)((const char*)ldsA + off);
    }
    int d = n0 + n;
    int kvg0 = TXT + rt * 64 + rc;
    size_t base = (((size_t)(b * NKT + (kvg0 >> 6))) << 14) + ((kvg0 >> 4) & 3) * 4096 + d * 16;
    *(short8*)(VTs + base) = o0;
    *(short8*)(VTs + base + 8) = o1;
  }
}

// ---------------- fused masked attention v15: register diet for 3 waves/SIMD ----------------
// r14 structure with ONE change: QK uses a SINGLE accumulator chain (16 sequential
// mfma32) instead of two. Saves 16 VGPRs: arch+AGPR total ~168 <= 512/3 -> 3 waves/SIMD
// (12 waves/CU) vs the 2-wave/SIMD cap (184 regs) that held occupancy at ~20% since r5.
// Dep-chain growth is covered by the extra co-resident wave.
__global__ __launch_bounds__(256, 2) void attn_kernel(
    const ushort_t* __restrict__ Qs, const ushort_t* __restrict__ Ks,
    const ushort_t* __restrict__ VTs, const ushort_t* __restrict__ sigp,
    float* __restrict__ out) {
  __shared__ __align__(16) ushort_t Kb[16384];      // 32KB  K(t)
  __shared__ __align__(16) ushort_t Pb[4096];       // 8KB   [32 rows][256B], XOR swz

  const int kblk = blockIdx.x;                      // 0..511
  const int bs = (kblk & 7) * 64 + (kblk >> 3);     // XCD-chunked bijective swizzle
  int g = bs * 34 + (bs >> 5);
  const int gend = (bs + 1) * 34 + ((bs + 1) >> 5);

  const int tid = threadIdx.x;
  const int wid = tid >> 6, lane = tid & 63;
  const int l31 = lane & 31, l5 = lane >> 5;
  const int qh = wid >> 1, kh = wid & 1;            // QK quarter
  const int d0 = wid * 64;                          // PV d-slice
  const int qloc = qh * 32 + l31;
  const int pkey = (l31 & 15) << 4;                 // 4-bit involutive XOR key

  int b = g / 1089, rem = g - b * 1089, qt = rem / 33, kvt = rem - qt * 33;

  short8 qf[16];
  int2 mq[4];

  auto ldq = [&](int bb, int qq) {
    const ushort_t* qb = Qs + (((size_t)(bb * NKT + qq)) << 14) + qloc * 16 + l5 * 8;
    #pragma unroll
    for (int ks = 0; ks < 16; ++ks) qf[ks] = *(const short8*)(qb + ks * 1024);
  };
  auto ldmask = [&](int qq, int tt) {
    int q = qq * 64 + qloc;
    int qc = q - TXT; qc = qc < 0 ? 0 : (qc > 2047 ? 2047 : qc);
    int kvp = tt * 64 + kh * 32 - TXT;
    int kvc = (kvp >= 0 && kvp <= 2016) ? kvp : 0;
    const char* mrow = (const char*)(sigp + (size_t)qc * 2048 + kvc) + l5 * 8;
    #pragma unroll
    for (int t = 0; t < 4; ++t) mq[t] = *(const int2*)(mrow + 16 * t);
  };
  auto stageK = [&](int bb, int tt) {
    const char* src = (const char*)Ks + (((size_t)(bb * NKT + tt)) << 15);
    #pragma unroll
    for (int m = 0; m < 8; ++m) { int s2 = m * 256 + tid; g2l16((char*)Kb + s2 * 16, src + s2 * 16); }
  };

  f32x16 oacc[2][2];
  #pragma unroll
  for (int i2 = 0; i2 < 2; ++i2)
    #pragma unroll
    for (int j2 = 0; j2 < 2; ++j2)
      #pragma unroll
      for (int r = 0; r < 16; ++r) oacc[i2][j2][r] = 0.f;

  auto flushO = [&](int bb, int qq) {
    #pragma unroll
    for (int qg2 = 0; qg2 < 2; ++qg2)
      #pragma unroll
      for (int dg = 0; dg < 2; ++dg)
        #pragma unroll
        for (int r = 0; r < 16; ++r) {
          int qg = qq * 64 + qg2 * 32 + (r & 3) + 8 * (r >> 2) + 4 * l5;
          int dd = d0 + dg * 32 + l31;
          if (qg < S_)
            unsafeAtomicAdd(&out[((size_t)bb * S_ + qg) * D_ + dd], oacc[qg2][dg][r]);
          oacc[qg2][dg][r] = 0.f;
        }
  };

  // ---- prologue ----
  stageK(b, kvt);
  ldmask(qt, kvt);
  ldq(b, qt);
  asm volatile("s_waitcnt vmcnt(0)" ::: "memory");
  __builtin_amdgcn_sched_barrier(0);
  __builtin_amdgcn_s_barrier();
  __builtin_amdgcn_sched_barrier(0);

  while (g < gend) {
    int gn = (g + 1 < GTOT) ? g + 1 : GTOT - 1;
    int nb = gn / 1089, nrem = gn - nb * 1089, nqt = nrem / 33, nkvt = nrem - nqt * 33;

    // ---- QK (S^T = K . Q^T): SINGLE accumulator chain (register diet) ----
    f32x16 s;
    #pragma unroll
    for (int r = 0; r < 16; ++r) s[r] = 0.f;
    const int arow = (kh * 32 + l31) * 32 + l5 * 16;
    __builtin_amdgcn_s_setprio(1);
    #pragma unroll
    for (int ks = 0; ks < 16; ++ks) {
      short8 ka = *(const short8*)((const char*)Kb + ks * 2048 + arow);
      s = mfma32(ka, qf[ks], s);
    }
    __builtin_amdgcn_s_setprio(0);

    // ---- mask + pack P (bf16) -> Pb (row = q&31, 256B rows, 4-bit XOR) ----
    {
      int q = qt * 64 + qloc;
      bool qv = (q >= TXT) && (q < S_);
      int kvp = kvt * 64 + kh * 32 - TXT;
      bool kvv = (kvp >= 0 && kvp <= 2016);
      bool ok = qv && kvv;
      #pragma unroll
      for (int t = 0; t < 4; ++t) {
        unsigned w0p, w1p;
        {
          unsigned w = (unsigned)mq[t].x;
          float m0 = ok ? bf2f((ushort_t)(w & 0xFFFFu)) : 1.0f;
          float m1 = ok ? bf2f((ushort_t)(w >> 16)) : 1.0f;
          int r = 4 * t;
          float p0 = s[r] * m0;
          float p1 = s[r + 1] * m1;
          asm("v_cvt_pk_bf16_f32 %0, %1, %2" : "=v"(w0p) : "v"(p0), "v"(p1));
        }
        {
          unsigned w = (unsigned)mq[t].y;
          float m0 = ok ? bf2f((ushort_t)(w & 0xFFFFu)) : 1.0f;
          float m1 = ok ? bf2f((ushort_t)(w >> 16)) : 1.0f;
          int r = 4 * t + 2;
          float p0 = s[r] * m0;
          float p1 = s[r + 1] * m1;
          asm("v_cvt_pk_bf16_f32 %0, %1, %2" : "=v"(w1p) : "v"(p0), "v"(p1));
        }
        int off = (l31 << 8) + (((qh << 7) + (kh << 6) + (t << 4) + (l5 << 3)) ^ pkey);
        *(uint2*)((char*)Pb + off) = make_uint2(w0p, w1p);
      }
    }

    asm volatile("s_waitcnt lgkmcnt(0)" ::: "memory");   // Kb reads + Pb writes done
    __builtin_amdgcn_sched_barrier(0);
    __builtin_amdgcn_s_barrier();          // barrier 1
    __builtin_amdgcn_sched_barrier(0);

    stageK(nb, nkvt);                      // K(t+1) into freed Kb
    __builtin_amdgcn_sched_barrier(0);

    // ---- PV: O[64q x 64d-slice] += P * V, V DIRECT from global ----
    const ushort_t* vb = VTs + (((size_t)(b * NKT + kvt)) << 14) + (size_t)d0 * 16 + l5 * 8;
    __builtin_amdgcn_s_setprio(1);
    #pragma unroll
    for (int ks = 0; ks < 4; ++ks) {
      short8 vf0 = *(const short8*)(vb + ks * 4096 + l31 * 16);
      short8 vf1 = *(const short8*)(vb + ks * 4096 + (l31 + 32) * 16);
      int p0 = (l31 << 8) + ((ks * 32 + l5 * 16) ^ pkey);
      int p1 = (l31 << 8) + ((128 + ks * 32 + l5 * 16) ^ pkey);
      short8 pf0 = *(const short8*)((const char*)Pb + p0);
      short8 pf1 = *(const short8*)((const char*)Pb + p1);
      oacc[0][0] = mfma32(pf0, vf0, oacc[0][0]);
      oacc[0][1] = mfma32(pf0, vf1, oacc[0][1]);
      oacc[1][0] = mfma32(pf1, vf0, oacc[1][0]);
      oacc[1][1] = mfma32(pf1, vf1, oacc[1][1]);
    }
    __builtin_amdgcn_s_setprio(0);
    asm volatile("s_waitcnt lgkmcnt(0)" ::: "memory");   // Pb reads retired
    __builtin_amdgcn_sched_barrier(0);

    // ---- tail: masks(t+1); ensure K(t+1) landed; flush at q boundaries ----
    ldmask(nqt, nkvt);                                   // 4 loads (newest)
    __builtin_amdgcn_sched_barrier(0);
    asm volatile("s_waitcnt vmcnt(4)" ::: "memory");     // K8 done; masks flying
    __builtin_amdgcn_sched_barrier(0);
    const bool qchange = (nqt != qt || nb != b);
    if (qchange) {                          // q-tile boundary (block-uniform)
      flushO(b, qt);
      ldq(nb, nqt);
    }
    __builtin_amdgcn_sched_barrier(0);
    __builtin_amdgcn_s_barrier();          // barrier 2: K(t+1)/P ready block-wide
    __builtin_amdgcn_sched_barrier(0);

    b = nb; qt = nqt; kvt = nkvt; ++g;
  }

  flushO(b, qt);
}

extern "C" void kernel_launch(void* const* d_in, const int* in_sizes, int n_in,
                              void* d_out, int out_size, void* d_ws, size_t ws_size,
                              hipStream_t stream) {
  (void)in_sizes; (void)n_in;
  const float* src   = (const float*)d_in[0];
  const float* learn = (const float*)d_in[1];
  const float* Wtq = (const float*)d_in[2];
  const float* Wtk = (const float*)d_in[3];
  const float* Wtv = (const float*)d_in[4];
  const float* Wvq = (const float*)d_in[5];
  const float* Wvk = (const float*)d_in[6];
  const float* Wvv = (const float*)d_in[7];
  float* out = (float*)d_out;

  char* ws = (char*)d_ws;
  const size_t QKV_ONE  = (size_t)B_ * SP * D_ * 2;
  const size_t QP_OFF   = 0;
  const size_t KS_OFF   = QP_OFF + QKV_ONE;
  const size_t VT_OFF   = KS_OFF + QKV_ONE;
  const size_t SIG_OFF  = VT_OFF + QKV_ONE;
  const size_t TBL_OFF  = SIG_OFF + (size_t)VID * VID * 2;
  const size_t WT_OFF   = TBL_OFF + (size_t)VID * 128 * 4 * sizeof(float);
  const size_t SRCB_OFF = WT_OFF + (size_t)3 * D_ * D_ * 2;
  const size_t NEED_SRCB = SRCB_OFF + (size_t)B_ * VID * D_ * 2;

  ushort_t* Qs   = (ushort_t*)(ws + QP_OFF);
  ushort_t* Ks   = (ushort_t*)(ws + KS_OFF);
  ushort_t* VTs  = (ushort_t*)(ws + VT_OFF);
  ushort_t* sigp = (ushort_t*)(ws + SIG_OFF);
  float*    tbl  = (float*)(ws + TBL_OFF);
  ushort_t* WT   = (ushort_t*)(ws + WT_OFF);
  ushort_t* srcb = (ushort_t*)(ws + SRCB_OFF);
  float*    loss = out + (size_t)B_ * S_ * D_;

  hipMemsetAsync(d_out, 0, (size_t)out_size * sizeof(float), stream);  // atomics + loss
  prep_kernel<<<3376, 256, 0, stream>>>(src, learn, Wtq, Wtk, Wtv, Wvq, Wvk, Wvv,
                                        Qs, Ks, VTs, sigp, tbl, WT, loss);
  if (ws_size >= NEED_SRCB) {
    cvt_kernel<<<4096, 256, 0, stream>>>(src, srcb);
    vid_gemm<1><<<dim3(32, B_, 12), 256, 0, stream>>>(src, srcb, WT, tbl, Qs, Ks, VTs);
  } else {
    vid_gemm<0><<<dim3(32, B_, 12), 256, 0, stream>>>(src, srcb, WT, tbl, Qs, Ks, VTs);
  }
  attn_kernel<<<dim3(512), 256, 0, stream>>>(Qs, Ks, VTs, sigp, out);
}

// Round 16
// 287.932 us; speedup vs baseline: 2.2588x; 1.0065x over previous
//
#include <hip/hip_runtime.h>

#define B_   16
#define TXT  32
#define VID  2048
#define D_   256
#define S_   2080
#define SP   2176   // padded sequence rows (34 tiles of 64)
#define NKT  34     // tiles (64 rows each) in Q/K/V subtiled layouts
#define GTOT 17424  // 16 b * 33 qt * 33 kv global iterations

typedef unsigned short ushort_t;
typedef __attribute__((ext_vector_type(8))) short short8;
typedef __attribute__((ext_vector_type(4))) short short4v;
typedef __attribute__((ext_vector_type(4))) float f32x4;
typedef __attribute__((ext_vector_type(16))) float f32x16;

__device__ __forceinline__ ushort_t f2bf(float f) {
  unsigned u = __builtin_bit_cast(unsigned, f);
  unsigned r = (u + 0x7FFFu + ((u >> 16) & 1u)) >> 16;   // RNE (finite values)
  return (ushort_t)r;
}
__device__ __forceinline__ float bf2f(ushort_t h) {
  unsigned u = ((unsigned)h) << 16;
  return __builtin_bit_cast(float, u);
}

__device__ __forceinline__ void g2l16(void* lds, const void* g) {
  __builtin_amdgcn_global_load_lds(
      (const __attribute__((address_space(1))) char*)g,
      (__attribute__((address_space(3))) char*)lds, 16, 0, 0);
}

__device__ __forceinline__ f32x4 mfma16(short8 a, short8 b, f32x4 c) {
  return __builtin_amdgcn_mfma_f32_16x16x32_bf16(a, b, c, 0, 0, 0);
}
__device__ __forceinline__ f32x16 mfma32(short8 a, short8 b, f32x16 c) {
  return __builtin_amdgcn_mfma_f32_32x32x16_bf16(a, b, c, 0, 0, 0);
}

// Subtiled layouts (per batch, per 64-row tile, 32KB = 16384 ushorts), all PLAIN:
//   Q/K: [kstep16][64 row][16 us]   (wave fragment reads are contiguous 1KB)
//   V:   [kvstep4][256 d][16 us]
// tile base (ushorts): (b*NKT + tile) << 14

// ---------------- merged producer kernel (now includes cvt branch) ----------------
// blocks: [0,64) txt | [64,112) wt | [112,1136) tbl | [1136,1328) pad0 | [1328,3376) sig
//         | [3376,7472) cvt (only launched when srcb fits in ws)
__global__ void prep_kernel(const float* __restrict__ src, const float* __restrict__ learn,
                            const float* __restrict__ Wtq, const float* __restrict__ Wtk,
                            const float* __restrict__ Wtv,
                            const float* __restrict__ Wvq, const float* __restrict__ Wvk,
                            const float* __restrict__ Wvv,
                            ushort_t* __restrict__ Qs, ushort_t* __restrict__ Ks,
                            ushort_t* __restrict__ VTs, ushort_t* __restrict__ sigp,
                            float* __restrict__ tbl, ushort_t* __restrict__ WT,
                            ushort_t* __restrict__ srcb,
                            float* __restrict__ loss) {
  __shared__ float shf[64 * 68];          // aliased per branch
  const int blk = blockIdx.x;
  const int tid = threadIdx.x;

  if (blk < 64) {
    // ---- txt rows: Q/K = (pos+x)W, V = xW ----
    float (*a_s)[256] = (float(*)[256])shf;
    float (*x_s)[256] = (float(*)[256])(shf + 2048);
    const int tg = blk & 3;
    const int b  = blk >> 2;
    const int c  = tid;
    #pragma unroll
    for (int t = 0; t < 8; ++t) {
      int row = tg * 8 + t;
      float x = src[((size_t)b * S_ + row) * D_ + c];
      float xe = (float)(row + 1) * (6.283185307179586f / (32.0f + 1e-6f));
      int i = c >> 1;
      float dimt = powf(10000.0f, (2.0f * (float)i) / 256.0f);
      float ang = xe / dimt;
      float pv = (c & 1) ? cosf(ang) : sinf(ang);
      x_s[t][c] = x;
      a_s[t][c] = x + pv;
    }
    __syncthreads();
    float q[8] = {0,0,0,0,0,0,0,0}, k[8] = {0,0,0,0,0,0,0,0}, v[8] = {0,0,0,0,0,0,0,0};
    for (int kk = 0; kk < 256; ++kk) {
      float wq = Wtq[(size_t)kk * 256 + c];
      float wk = Wtk[(size_t)kk * 256 + c];
      float wv = Wtv[(size_t)kk * 256 + c];
      #pragma unroll
      for (int t = 0; t < 8; ++t) {
        q[t] = fmaf(a_s[t][kk], wq, q[t]);
        k[t] = fmaf(a_s[t][kk], wk, k[t]);
        v[t] = fmaf(x_s[t][kk], wv, v[t]);
      }
    }
    #pragma unroll
    for (int t = 0; t < 8; ++t) {
      int row = tg * 8 + t;          // rows 0..31 => tile 0
      size_t base = ((size_t)(b * NKT)) << 14;
      size_t sub = (size_t)(c >> 4) * 1024 + row * 16 + (c & 15);
      Qs[base + sub] = f2bf(q[t]);
      Ks[base + sub] = f2bf(k[t]);
      VTs[base + (size_t)(row >> 4) * 4096 + c * 16 + (row & 15)] = f2bf(v[t]);
    }
  } else if (blk < 112) {
    // ---- weight transpose: WT[mat][n][k] = W[k][n] ----
    float (*t)[68] = (float(*)[68])shf;
    const int m = blk - 64;
    const int k0 = (m & 3) * 64, n0 = ((m >> 2) & 3) * 64, mt = m >> 4;
    const float* W = (mt == 0) ? Wvq : (mt == 1) ? Wvk : Wvv;
    int r = tid >> 4, cq = (tid & 15) * 4;
    #pragma unroll
    for (int mm = 0; mm < 4; ++mm) {
      int k = mm * 16 + r;
      float4 v = *(const float4*)(W + (size_t)(k0 + k) * 256 + n0 + cq);
      t[k][cq] = v.x; t[k][cq + 1] = v.y; t[k][cq + 2] = v.z; t[k][cq + 3] = v.w;
    }
    __syncthreads();
    #pragma unroll
    for (int mm = 0; mm < 4; ++mm) {
      int n = mm * 16 + r;
      short4v h;
      h[0] = (short)f2bf(t[cq + 0][n]);
      h[1] = (short)f2bf(t[cq + 1][n]);
      h[2] = (short)f2bf(t[cq + 2][n]);
      h[3] = (short)f2bf(t[cq + 3][n]);
      *(short4v*)(WT + ((size_t)mt * D_ + n0 + n) * D_ + k0 + cq) = h;
    }
  } else if (blk < 1136) {
    // ---- xpos table ----
    int idx = (blk - 112) * 256 + tid;
    int n = idx >> 7, i = idx & 127;
    float invf = powf(10000.0f, -(float)i / 128.0f);
    float ang = (float)n * invf;
    float s, co;
    sincosf(ang, &s, &co);
    float sv = ((float)(2 * i) + 102.4f) / 358.4f;
    float sc = powf(sv, (float)n / 512.0f);
    float4 r;
    r.x = co * sc; r.y = s * sc; r.z = co / sc; r.w = s / sc;
    *(float4*)(tbl + (size_t)idx * 4) = r;
  } else if (blk < 1328) {
    // ---- zero-fill padding (tile 32: Q/K rows 32..63, V kvsteps 2..3) ----
    int i = (blk - 1136) * 256 + tid;           // 49152 total
    short8 z = {0, 0, 0, 0, 0, 0, 0, 0};
    int sec = i >> 14;
    int j = i & 16383;
    int bb = j >> 10;
    int rem = j & 1023;
    size_t base = ((size_t)(bb * NKT + 32)) << 14;
    if (sec == 0) {
      int kstep = rem >> 6, ch = rem & 63;
      *(short8*)(Qs + base + kstep * 1024 + 512 + ch * 8) = z;
    } else if (sec == 1) {
      int kstep = rem >> 6, ch = rem & 63;
      *(short8*)(Ks + base + kstep * 1024 + 512 + ch * 8) = z;
    } else {
      *(short8*)(VTs + base + 8192 + rem * 8) = z;
    }
  } else if (blk < 3376) {
    // ---- sigmoid mask (row-major bf16) + sparsity loss ----
    float* red = shf;
    const int base = ((blk - 1328) * 256 + tid) * 8;
    float4 v0 = *(const float4*)(learn + base);
    float4 v1 = *(const float4*)(learn + base + 4);
    float vals[8] = {v0.x, v0.y, v0.z, v0.w, v1.x, v1.y, v1.z, v1.w};
    float acc = 0.f;
    short8 sh;
    #pragma unroll
    for (int j = 0; j < 8; ++j) {
      int idx = base + j;
      float s = 1.0f / (1.0f + expf(-vals[j]));
      sh[j] = (short)f2bf(s);
      int rr = idx >> 11, cc = idx & 2047;
      if (rr != cc) acc += s;
    }
    *(short8*)(sigp + base) = sh;
    red[tid] = acc;
    __syncthreads();
    #pragma unroll
    for (int st = 128; st > 0; st >>= 1) {
      if (tid < st) red[tid] += red[tid + st];
      __syncthreads();
    }
    if (tid == 0) atomicAdd(loss, red[0] * (1.0f / 4194304.0f));
  } else {
    // ---- cvt: src vid rows -> bf16 srcb (for vid_gemm MODE 1) ----
    int i = (blk - 3376) * 256 + tid;           // 1,048,576 total
    int b = i >> 16;
    int rem = i & 65535;
    int row = rem >> 5, c8 = (rem & 31) * 8;
    const float* p = src + ((size_t)b * S_ + TXT + row) * D_ + c8;
    float4 v0 = *(const float4*)p;
    float4 v1 = *(const float4*)(p + 4);
    short8 h;
    h[0] = (short)f2bf(v0.x); h[1] = (short)f2bf(v0.y); h[2] = (short)f2bf(v0.z); h[3] = (short)f2bf(v0.w);
    h[4] = (short)f2bf(v1.x); h[5] = (short)f2bf(v1.y); h[6] = (short)f2bf(v1.z); h[7] = (short)f2bf(v1.w);
    *(short8*)(srcb + ((size_t)b * VID + row) * D_ + c8) = h;
  }
}

// ---------------- vid projection GEMM (per-tile grid, +xpos epilogue) ----------------
// MODE 0: A from f32 src (cvt in-kernel).  MODE 1: A via g2l16 from bf16 srcb (pre-XOR'd source).
template <int MODE>
__global__ __launch_bounds__(256, 2) void vid_gemm(
    const float* __restrict__ src, const ushort_t* __restrict__ srcb,
    const ushort_t* __restrict__ WT, const float* __restrict__ tbl,
    ushort_t* __restrict__ Qs, ushort_t* __restrict__ Ks, ushort_t* __restrict__ VTs) {
  __shared__ __align__(16) ushort_t ldsA[64 * 64];
  __shared__ __align__(16) ushort_t ldsB[64 * 64];

  const int rt = blockIdx.x;
  const int b  = blockIdx.y;
  const int ct = blockIdx.z;
  const int nt = ct >> 2;
  const int n0 = (ct & 3) * 64;
  const int tid = threadIdx.x;
  const int wv = tid >> 6, lane = tid & 63, l15 = lane & 15, l4 = lane >> 4;

  f32x4 acc[4];
  #pragma unroll
  for (int t2 = 0; t2 < 4; ++t2) { acc[t2][0] = 0.f; acc[t2][1] = 0.f; acc[t2][2] = 0.f; acc[t2][3] = 0.f; }

  for (int kk = 0; kk < 256; kk += 64) {
    if (MODE == 1) {
      #pragma unroll
      for (int m = 0; m < 2; ++m) {
        int p = (m * 256 + tid) * 16;
        int r = p >> 7;
        int cb = (p & 127) ^ ((r & 7) << 4);
        g2l16((char*)ldsA + p,
              (const char*)(srcb + ((size_t)b * VID + rt * 64 + r) * D_ + kk) + cb);
      }
    } else {
      #pragma unroll
      for (int m = 0; m < 4; ++m) {
        int q = m * 256 + tid;
        int r = q >> 4;
        int kc = (q & 15) * 4;
        const float4 v = *(const float4*)(src + ((size_t)b * S_ + TXT + rt * 64 + r) * D_ + kk + kc);
        short4v h;
        h[0] = (short)f2bf(v.x); h[1] = (short)f2bf(v.y);
        h[2] = (short)f2bf(v.z); h[3] = (short)f2bf(v.w);
        int off = ((r << 7) + (kc << 1)) ^ ((r & 7) << 4);
        *(short4v*)((char*)ldsA + off) = h;
      }
    }
    #pragma unroll
    for (int m = 0; m < 2; ++m) {
      int p = (m * 256 + tid) * 16;
      int nl = p >> 7;
      int c = (p & 127) ^ ((nl & 7) << 4);
      g2l16((char*)ldsB + p, (const char*)(WT + ((size_t)nt * D_ + n0 + nl) * D_ + kk) + c);
    }
    __syncthreads();
    #pragma unroll
    for (int ks = 0; ks < 2; ++ks) {
      int ar = wv * 16 + l15;
      int aoff = ((ar << 7) + ((ks * 32 + l4 * 8) << 1)) ^ ((ar & 7) << 4);
      short8 av = *(const short8*)((const char*)ldsA + aoff);
      #pragma unroll
      for (int t2 = 0; t2 < 4; ++t2) {
        int nl = t2 * 16 + l15;
        int boff = ((nl << 7) + ((ks * 32 + l4 * 8) << 1)) ^ ((nl & 7) << 4);
        short8 bv = *(const short8*)((const char*)ldsB + boff);
        acc[t2] = mfma16(av, bv, acc[t2]);
      }
    }
    __syncthreads();
  }

  const int rowl = wv * 16 + l4 * 4;
  if (nt < 2) {
    #pragma unroll
    for (int t2 = 0; t2 < 4; ++t2) {
      int c = n0 + t2 * 16 + l15;
      #pragma unroll
      for (int r = 0; r < 4; ++r) {
        int n = rt * 64 + rowl + r;
        float x = acc[t2][r];
        float xp = __shfl_xor(x, 1);
        const float4 tb = *(const float4*)(tbl + ((size_t)n * 128 + (c >> 1)) * 4);
        float cs = (nt == 0) ? tb.x : tb.z;
        float ss = (nt == 0) ? tb.y : tb.w;
        float val = (c & 1) ? fmaf(x, cs, xp * ss) : fmaf(x, cs, -xp * ss);
        int rowg = TXT + n;
        size_t idx = (((size_t)(b * NKT + (rowg >> 6))) << 14)
                   + (size_t)(c >> 4) * 1024 + (rowg & 63) * 16 + (c & 15);
        if (nt == 0) Qs[idx] = f2bf(val);
        else         Ks[idx] = f2bf(val);
      }
    }
  } else {
    #pragma unroll
    for (int t2 = 0; t2 < 4; ++t2)
      #pragma unroll
      for (int r = 0; r < 4; ++r) {
        int rr = rowl + r;
        int cc = t2 * 16 + l15;
        int off = ((rr << 7) + (cc << 1)) ^ ((rr & 7) << 4);
        *(ushort_t*)((char*)ldsA + off) = f2bf(acc[t2][r]);
      }
    __syncthreads();
    int n = tid >> 2;
    int rc = (tid & 3) * 16;
    short8 o0, o1;
    #pragma unroll
    for (int j = 0; j < 8; ++j) {
      int rr = rc + j;
      int off = ((rr << 7) + (n << 1)) ^ ((rr & 7) << 4);
      o0[j] = *(const short*)((const char*)ldsA + off);
    }
    #pragma unroll
    for (int j = 0; j < 8; ++j) {
      int rr = rc + 8 + j;
      int off = ((rr << 7) + (n << 1)) ^ ((rr & 7) << 4);
      o1[j] = *(const short*)((const char*)ldsA + off);
    }
    int d = n0 + n;
    int kvg0 = TXT + rt * 64 + rc;
    size_t base = (((size_t)(b * NKT + (kvg0 >> 6))) << 14) + ((kvg0 >> 4) & 3) * 4096 + d * 16;
    *(short8*)(VTs + base) = o0;
    *(short8*)(VTs + base + 8) = o1;
  }
}

// ---------------- fused masked attention v15 (unchanged): 40KB LDS, V direct ----------------
__global__ __launch_bounds__(256, 2) void attn_kernel(
    const ushort_t* __restrict__ Qs, const ushort_t* __restrict__ Ks,
    const ushort_t* __restrict__ VTs, const ushort_t* __restrict__ sigp,
    float* __restrict__ out) {
  __shared__ __align__(16) ushort_t Kb[16384];      // 32KB  K(t)
  __shared__ __align__(16) ushort_t Pb[4096];       // 8KB   [32 rows][256B], XOR swz

  const int kblk = blockIdx.x;                      // 0..511
  const int bs = (kblk & 7) * 64 + (kblk >> 3);     // XCD-chunked bijective swizzle
  int g = bs * 34 + (bs >> 5);
  const int gend = (bs + 1) * 34 + ((bs + 1) >> 5);

  const int tid = threadIdx.x;
  const int wid = tid >> 6, lane = tid & 63;
  const int l31 = lane & 31, l5 = lane >> 5;
  const int qh = wid >> 1, kh = wid & 1;            // QK quarter
  const int d0 = wid * 64;                          // PV d-slice
  const int qloc = qh * 32 + l31;
  const int pkey = (l31 & 15) << 4;                 // 4-bit involutive XOR key

  int b = g / 1089, rem = g - b * 1089, qt = rem / 33, kvt = rem - qt * 33;

  short8 qf[16];
  int2 mq[4];

  auto ldq = [&](int bb, int qq) {
    const ushort_t* qb = Qs + (((size_t)(bb * NKT + qq)) << 14) + qloc * 16 + l5 * 8;
    #pragma unroll
    for (int ks = 0; ks < 16; ++ks) qf[ks] = *(const short8*)(qb + ks * 1024);
  };
  auto ldmask = [&](int qq, int tt) {
    int q = qq * 64 + qloc;
    int qc = q - TXT; qc = qc < 0 ? 0 : (qc > 2047 ? 2047 : qc);
    int kvp = tt * 64 + kh * 32 - TXT;
    int kvc = (kvp >= 0 && kvp <= 2016) ? kvp : 0;
    const char* mrow = (const char*)(sigp + (size_t)qc * 2048 + kvc) + l5 * 8;
    #pragma unroll
    for (int t = 0; t < 4; ++t) mq[t] = *(const int2*)(mrow + 16 * t);
  };
  auto stageK = [&](int bb, int tt) {
    const char* src = (const char*)Ks + (((size_t)(bb * NKT + tt)) << 15);
    #pragma unroll
    for (int m = 0; m < 8; ++m) { int s2 = m * 256 + tid; g2l16((char*)Kb + s2 * 16, src + s2 * 16); }
  };

  f32x16 oacc[2][2];
  #pragma unroll
  for (int i2 = 0; i2 < 2; ++i2)
    #pragma unroll
    for (int j2 = 0; j2 < 2; ++j2)
      #pragma unroll
      for (int r = 0; r < 16; ++r) oacc[i2][j2][r] = 0.f;

  auto flushO = [&](int bb, int qq) {
    #pragma unroll
    for (int qg2 = 0; qg2 < 2; ++qg2)
      #pragma unroll
      for (int dg = 0; dg < 2; ++dg)
        #pragma unroll
        for (int r = 0; r < 16; ++r) {
          int qg = qq * 64 + qg2 * 32 + (r & 3) + 8 * (r >> 2) + 4 * l5;
          int dd = d0 + dg * 32 + l31;
          if (qg < S_)
            unsafeAtomicAdd(&out[((size_t)bb * S_ + qg) * D_ + dd], oacc[qg2][dg][r]);
          oacc[qg2][dg][r] = 0.f;
        }
  };

  // ---- prologue ----
  stageK(b, kvt);
  ldmask(qt, kvt);
  ldq(b, qt);
  asm volatile("s_waitcnt vmcnt(0)" ::: "memory");
  __builtin_amdgcn_sched_barrier(0);
  __builtin_amdgcn_s_barrier();
  __builtin_amdgcn_sched_barrier(0);

  while (g < gend) {
    int gn = (g + 1 < GTOT) ? g + 1 : GTOT - 1;
    int nb = gn / 1089, nrem = gn - nb * 1089, nqt = nrem / 33, nkvt = nrem - nqt * 33;

    // ---- QK (S^T = K . Q^T): SINGLE accumulator chain ----
    f32x16 s;
    #pragma unroll
    for (int r = 0; r < 16; ++r) s[r] = 0.f;
    const int arow = (kh * 32 + l31) * 32 + l5 * 16;
    __builtin_amdgcn_s_setprio(1);
    #pragma unroll
    for (int ks = 0; ks < 16; ++ks) {
      short8 ka = *(const short8*)((const char*)Kb + ks * 2048 + arow);
      s = mfma32(ka, qf[ks], s);
    }
    __builtin_amdgcn_s_setprio(0);

    // ---- mask + pack P (bf16) -> Pb (row = q&31, 256B rows, 4-bit XOR) ----
    {
      int q = qt * 64 + qloc;
      bool qv = (q >= TXT) && (q < S_);
      int kvp = kvt * 64 + kh * 32 - TXT;
      bool kvv = (kvp >= 0 && kvp <= 2016);
      bool ok = qv && kvv;
      #pragma unroll
      for (int t = 0; t < 4; ++t) {
        unsigned w0p, w1p;
        {
          unsigned w = (unsigned)mq[t].x;
          float m0 = ok ? bf2f((ushort_t)(w & 0xFFFFu)) : 1.0f;
          float m1 = ok ? bf2f((ushort_t)(w >> 16)) : 1.0f;
          int r = 4 * t;
          float p0 = s[r] * m0;
          float p1 = s[r + 1] * m1;
          asm("v_cvt_pk_bf16_f32 %0, %1, %2" : "=v"(w0p) : "v"(p0), "v"(p1));
        }
        {
          unsigned w = (unsigned)mq[t].y;
          float m0 = ok ? bf2f((ushort_t)(w & 0xFFFFu)) : 1.0f;
          float m1 = ok ? bf2f((ushort_t)(w >> 16)) : 1.0f;
          int r = 4 * t + 2;
          float p0 = s[r] * m0;
          float p1 = s[r + 1] * m1;
          asm("v_cvt_pk_bf16_f32 %0, %1, %2" : "=v"(w1p) : "v"(p0), "v"(p1));
        }
        int off = (l31 << 8) + (((qh << 7) + (kh << 6) + (t << 4) + (l5 << 3)) ^ pkey);
        *(uint2*)((char*)Pb + off) = make_uint2(w0p, w1p);
      }
    }

    asm volatile("s_waitcnt lgkmcnt(0)" ::: "memory");   // Kb reads + Pb writes done
    __builtin_amdgcn_sched_barrier(0);
    __builtin_amdgcn_s_barrier();          // barrier 1
    __builtin_amdgcn_sched_barrier(0);

    stageK(nb, nkvt);                      // K(t+1) into freed Kb
    __builtin_amdgcn_sched_barrier(0);

    // ---- PV: O[64q x 64d-slice] += P * V, V DIRECT from global ----
    const ushort_t* vb = VTs + (((size_t)(b * NKT + kvt)) << 14) + (size_t)d0 * 16 + l5 * 8;
    __builtin_amdgcn_s_setprio(1);
    #pragma unroll
    for (int ks = 0; ks < 4; ++ks) {
      short8 vf0 = *(const short8*)(vb + ks * 4096 + l31 * 16);
      short8 vf1 = *(const short8*)(vb + ks * 4096 + (l31 + 32) * 16);
      int p0 = (l31 << 8) + ((ks * 32 + l5 * 16) ^ pkey);
      int p1 = (l31 << 8) + ((128 + ks * 32 + l5 * 16) ^ pkey);
      short8 pf0 = *(const short8*)((const char*)Pb + p0);
      short8 pf1 = *(const short8*)((const char*)Pb + p1);
      oacc[0][0] = mfma32(pf0, vf0, oacc[0][0]);
      oacc[0][1] = mfma32(pf0, vf1, oacc[0][1]);
      oacc[1][0] = mfma32(pf1, vf0, oacc[1][0]);
      oacc[1][1] = mfma32(pf1, vf1, oacc[1][1]);
    }
    __builtin_amdgcn_s_setprio(0);
    asm volatile("s_waitcnt lgkmcnt(0)" ::: "memory");   // Pb reads retired
    __builtin_amdgcn_sched_barrier(0);

    // ---- tail: masks(t+1); ensure K(t+1) landed; flush at q boundaries ----
    ldmask(nqt, nkvt);                                   // 4 loads (newest)
    __builtin_amdgcn_sched_barrier(0);
    asm volatile("s_waitcnt vmcnt(4)" ::: "memory");     // K8 done; masks flying
    __builtin_amdgcn_sched_barrier(0);
    const bool qchange = (nqt != qt || nb != b);
    if (qchange) {                          // q-tile boundary (block-uniform)
      flushO(b, qt);
      ldq(nb, nqt);
    }
    __builtin_amdgcn_sched_barrier(0);
    __builtin_amdgcn_s_barrier();          // barrier 2: K(t+1)/P ready block-wide
    __builtin_amdgcn_sched_barrier(0);

    b = nb; qt = nqt; kvt = nkvt; ++g;
  }

  flushO(b, qt);
}

extern "C" void kernel_launch(void* const* d_in, const int* in_sizes, int n_in,
                              void* d_out, int out_size, void* d_ws, size_t ws_size,
                              hipStream_t stream) {
  (void)in_sizes; (void)n_in;
  const float* src   = (const float*)d_in[0];
  const float* learn = (const float*)d_in[1];
  const float* Wtq = (const float*)d_in[2];
  const float* Wtk = (const float*)d_in[3];
  const float* Wtv = (const float*)d_in[4];
  const float* Wvq = (const float*)d_in[5];
  const float* Wvk = (const float*)d_in[6];
  const float* Wvv = (const float*)d_in[7];
  float* out = (float*)d_out;

  char* ws = (char*)d_ws;
  const size_t QKV_ONE  = (size_t)B_ * SP * D_ * 2;
  const size_t QP_OFF   = 0;
  const size_t KS_OFF   = QP_OFF + QKV_ONE;
  const size_t VT_OFF   = KS_OFF + QKV_ONE;
  const size_t SIG_OFF  = VT_OFF + QKV_ONE;
  const size_t TBL_OFF  = SIG_OFF + (size_t)VID * VID * 2;
  const size_t WT_OFF   = TBL_OFF + (size_t)VID * 128 * 4 * sizeof(float);
  const size_t SRCB_OFF = WT_OFF + (size_t)3 * D_ * D_ * 2;
  const size_t NEED_SRCB = SRCB_OFF + (size_t)B_ * VID * D_ * 2;

  ushort_t* Qs   = (ushort_t*)(ws + QP_OFF);
  ushort_t* Ks   = (ushort_t*)(ws + KS_OFF);
  ushort_t* VTs  = (ushort_t*)(ws + VT_OFF);
  ushort_t* sigp = (ushort_t*)(ws + SIG_OFF);
  float*    tbl  = (float*)(ws + TBL_OFF);
  ushort_t* WT   = (ushort_t*)(ws + WT_OFF);
  ushort_t* srcb = (ushort_t*)(ws + SRCB_OFF);
  float*    loss = out + (size_t)B_ * S_ * D_;

  const bool mode1 = (ws_size >= NEED_SRCB);

  hipMemsetAsync(d_out, 0, (size_t)out_size * sizeof(float), stream);  // atomics + loss
  prep_kernel<<<mode1 ? 7472 : 3376, 256, 0, stream>>>(
      src, learn, Wtq, Wtk, Wtv, Wvq, Wvk, Wvv,
      Qs, Ks, VTs, sigp, tbl, WT, srcb, loss);
  if (mode1) {
    vid_gemm<1><<<dim3(32, B_, 12), 256, 0, stream>>>(src, srcb, WT, tbl, Qs, Ks, VTs);
  } else {
    vid_gemm<0><<<dim3(32, B_, 12), 256, 0, stream>>>(src, srcb, WT, tbl, Qs, Ks, VTs);
  }
  attn_kernel<<<dim3(512), 256, 0, stream>>>(Qs, Ks, VTs, sigp, out);
}